// Round 1
// baseline (5903.170 us; speedup 1.0000x reference)
//
#include <hip/hip_runtime.h>
#include <hip/hip_bf16.h>
#include <math.h>

// Problem constants
#define BATCH 2
#define SEQ 2048
#define DMODEL 1024
#define HEADS 16
#define HSIZE 64
#define FREQS 256
#define NH (HEADS * HSIZE)   // 1024
#define QKVN (3 * NH)        // 3072

// ---------------------------------------------------------------------------
// Sinusoid table: sins[s][f] = sqrt(2) * (f even ? sin(s*invf) : cos(s*invf))
// invf = 10000^(-((f//2)*2)/256). Computed in double to match numpy float64.
// ---------------------------------------------------------------------------
__global__ void sins_kernel(float* __restrict__ sins) {
    int i = blockIdx.x * blockDim.x + threadIdx.x;
    if (i >= SEQ * FREQS) return;
    int s = i >> 8;          // /256
    int f = i & 255;
    double e = -(double)((f >> 1) << 1) / (double)FREQS;
    double invf = pow(10000.0, e);
    double ang = (double)s * invf;
    double v = (f & 1) ? cos(ang) : sin(ang);
    sins[i] = (float)(1.4142135623730951 * v);
}

// ---------------------------------------------------------------------------
// Generic fp32 tiled GEMM: C[M][N] = alpha * A[M][K] @ B[K][N] (+ bias)
// bias_mode 0: none; 1: add bias[col] if col < 1024 (qkv / q_bias);
// 2: add bias[col] (out_bias).
// Requires M%64==0, N%64==0, K%16==0.
// ---------------------------------------------------------------------------
#define BM 64
#define BN 64
#define BK 16

__global__ __launch_bounds__(256) void gemm_kernel(
    const float* __restrict__ A, const float* __restrict__ B,
    float* __restrict__ C, int M, int N, int K, float alpha,
    const float* __restrict__ bias, int bias_mode)
{
    __shared__ __align__(16) float As[BK][BM + 1];  // transposed: As[k][m]
    __shared__ __align__(16) float Bs[BK][BN];

    const int t  = threadIdx.x;
    const int m0 = blockIdx.y * BM;
    const int n0 = blockIdx.x * BN;
    const int tx = t & 15;          // 0..15 -> 4 cols each
    const int ty = t >> 4;          // 0..15 -> 4 rows each

    // A-tile load coords: 64 rows x 16 cols, float4 per thread
    const int ar  = t >> 2;         // 0..63
    const int ac4 = (t & 3) * 4;    // 0,4,8,12
    // B-tile load coords: 16 rows x 64 cols, float4 per thread
    const int br  = t >> 4;         // 0..15
    const int bc4 = (t & 15) * 4;   // 0..60

    float acc[4][4] = {};

    for (int k0 = 0; k0 < K; k0 += BK) {
        float4 av = *(const float4*)(A + (size_t)(m0 + ar) * K + k0 + ac4);
        As[ac4 + 0][ar] = av.x;
        As[ac4 + 1][ar] = av.y;
        As[ac4 + 2][ar] = av.z;
        As[ac4 + 3][ar] = av.w;
        float4 bv = *(const float4*)(B + (size_t)(k0 + br) * N + n0 + bc4);
        *(float4*)(&Bs[br][bc4]) = bv;
        __syncthreads();

#pragma unroll
        for (int kk = 0; kk < BK; kk++) {
            float a[4], b[4];
#pragma unroll
            for (int i = 0; i < 4; i++) a[i] = As[kk][ty * 4 + i];
#pragma unroll
            for (int j = 0; j < 4; j++) b[j] = Bs[kk][tx * 4 + j];
#pragma unroll
            for (int i = 0; i < 4; i++)
#pragma unroll
                for (int j = 0; j < 4; j++) acc[i][j] += a[i] * b[j];
        }
        __syncthreads();
    }

#pragma unroll
    for (int i = 0; i < 4; i++) {
        int row = m0 + ty * 4 + i;
#pragma unroll
        for (int j = 0; j < 4; j++) {
            int col = n0 + tx * 4 + j;
            float v = acc[i][j] * alpha;
            if (bias_mode == 1) {
                if (col < NH) v += bias[col];
            } else if (bias_mode == 2) {
                v += bias[col];
            }
            C[(size_t)row * N + col] = v;
        }
    }
}

// ---------------------------------------------------------------------------
// Attention: one block (256 threads) per (b, n, q) row.
// qkv layout: [b][s][3][n*h]  (direct output of QKV GEMM, rows b*s, cols 3072)
// emb layout: [s][n*h]        (direct output of emb GEMM)
// o   layout: [b][s][n*h]
// score(q,k) = 0.125 * sum_h qv[h] * (K[k][h] + emb[q-k][h]),  k <= q
// ---------------------------------------------------------------------------
__global__ __launch_bounds__(256) void attn_kernel(
    const float* __restrict__ qkv, const float* __restrict__ emb,
    float* __restrict__ o)
{
    __shared__ float qv[HSIZE];
    __shared__ float sc[SEQ];
    __shared__ float red[256];
    __shared__ float oacc[4][HSIZE];

    const int q  = blockIdx.x;
    const int bn = blockIdx.y;
    const int b  = bn >> 4;
    const int n  = bn & 15;
    const int t  = threadIdx.x;

    const size_t row_base = ((size_t)(b * SEQ) ) * QKVN;   // + s*QKVN
    // load q vector (+ bias already applied in GEMM epilogue)
    if (t < HSIZE) {
        qv[t] = qkv[((size_t)(b * SEQ + q)) * QKVN + n * HSIZE + t];
    }
    __syncthreads();

    // --- scores + local max ---
    float lmax = -1e30f;
    for (int k = t; k <= q; k += 256) {
        const float4* kp = (const float4*)(qkv + ((size_t)(b * SEQ + k)) * QKVN + NH + n * HSIZE);
        const float4* ep = (const float4*)(emb + (size_t)(q - k) * NH + n * HSIZE);
        float dot = 0.0f;
#pragma unroll
        for (int h4 = 0; h4 < 16; h4++) {
            float4 kv = kp[h4];
            float4 ev = ep[h4];
            dot += qv[h4 * 4 + 0] * (kv.x + ev.x);
            dot += qv[h4 * 4 + 1] * (kv.y + ev.y);
            dot += qv[h4 * 4 + 2] * (kv.z + ev.z);
            dot += qv[h4 * 4 + 3] * (kv.w + ev.w);
        }
        float s = dot * 0.125f;
        sc[k] = s;
        lmax = fmaxf(lmax, s);
    }

    // --- block max reduce ---
    red[t] = lmax;
    __syncthreads();
    for (int s2 = 128; s2 > 0; s2 >>= 1) {
        if (t < s2) red[t] = fmaxf(red[t], red[t + s2]);
        __syncthreads();
    }
    const float m = red[0];
    __syncthreads();

    // --- exp + local sum ---
    float lsum = 0.0f;
    for (int k = t; k <= q; k += 256) {
        float p = expf(sc[k] - m);
        sc[k] = p;
        lsum += p;
    }
    red[t] = lsum;
    __syncthreads();
    for (int s2 = 128; s2 > 0; s2 >>= 1) {
        if (t < s2) red[t] += red[t + s2];
        __syncthreads();
    }
    const float l = red[0];
    __syncthreads();

    // --- o[h] = sum_k p[k] * V[k][h] / l ---
    const int h = t & 63;
    const int c = t >> 6;   // 4 chunks (one per wave)
    float acc = 0.0f;
    for (int k = c; k <= q; k += 4) {
        acc += sc[k] * qkv[((size_t)(b * SEQ + k)) * QKVN + 2 * NH + n * HSIZE + h];
    }
    oacc[c][h] = acc;
    __syncthreads();
    if (t < HSIZE) {
        float s = (oacc[0][t] + oacc[1][t] + oacc[2][t] + oacc[3][t]) / l;
        o[((size_t)(b * SEQ + q)) * NH + n * HSIZE + t] = s;
    }
    (void)row_base;
}

// ---------------------------------------------------------------------------
extern "C" void kernel_launch(void* const* d_in, const int* in_sizes, int n_in,
                              void* d_out, int out_size, void* d_ws, size_t ws_size,
                              hipStream_t stream) {
    const float* inp        = (const float*)d_in[0];  // (2, 2048, 1024)
    const float* qkv_w      = (const float*)d_in[1];  // (1024, 3072)
    const float* q_bias     = (const float*)d_in[2];  // (1024,)
    const float* positional = (const float*)d_in[3];  // (256, 1024)
    const float* out_kernel = (const float*)d_in[4];  // (1024, 1024)
    const float* out_bias   = (const float*)d_in[5];  // (1024,)
    float* out = (float*)d_out;                       // (2, 2048, 1024)

    float* ws      = (float*)d_ws;
    float* qkv_out = ws;                              // 4096*3072 = 12,582,912
    float* sins    = qkv_out + (size_t)BATCH * SEQ * QKVN;   // 2048*256
    float* emb     = sins + (size_t)SEQ * FREQS;             // 2048*1024
    float* attn    = emb + (size_t)SEQ * NH;                 // 4096*1024

    const float qkv_scale = (float)pow(3.0 * DMODEL * HSIZE * HEADS, -0.25);
    const float emb_scale = 0.0625f;    // 256^-0.5
    const float out_scale = 0.03125f;   // (1024*1024)^-0.25

    // 1. sinusoid table
    sins_kernel<<<(SEQ * FREQS + 255) / 256, 256, 0, stream>>>(sins);

    // 2. QKV projection: (4096 x 3072) = inp (4096 x 1024) @ qkv_w (1024 x 3072)
    gemm_kernel<<<dim3(QKVN / BN, (BATCH * SEQ) / BM), 256, 0, stream>>>(
        inp, qkv_w, qkv_out, BATCH * SEQ, QKVN, DMODEL, qkv_scale, q_bias, 1);

    // 3. emb: (2048 x 1024) = sins (2048 x 256) @ positional (256 x 1024)
    gemm_kernel<<<dim3(NH / BN, SEQ / BM), 256, 0, stream>>>(
        sins, positional, emb, SEQ, NH, FREQS, emb_scale, nullptr, 0);

    // 4. attention
    attn_kernel<<<dim3(SEQ, BATCH * HEADS), 256, 0, stream>>>(qkv_out, emb, attn);

    // 5. output projection: (4096 x 1024) = attn @ out_kernel (1024 x 1024)
    gemm_kernel<<<dim3(NH / BN, (BATCH * SEQ) / BM), 256, 0, stream>>>(
        attn, out_kernel, out, BATCH * SEQ, NH, DMODEL, out_scale, out_bias, 2);
}

// Round 2
// 779.951 us; speedup vs baseline: 7.5686x; 7.5686x over previous
//
#include <hip/hip_runtime.h>
#include <math.h>

#define BATCH 2
#define SEQ 2048
#define DMODEL 1024
#define HEADS 16
#define HSIZE 64
#define FREQS 256
#define NH 1024
#define QKVN 3072

typedef __bf16 bf16;
typedef __bf16 bf16x8 __attribute__((ext_vector_type(8)));
typedef float f32x4 __attribute__((ext_vector_type(4)));

static __device__ __forceinline__ unsigned short bf16_bits(float v) {
    bf16 b = (bf16)v;
    return __builtin_bit_cast(unsigned short, b);
}

// ---------------------------------------------------------------------------
// Sinusoid table (fp64 to match numpy): sins[s][f]
// ---------------------------------------------------------------------------
__global__ void sins_kernel(float* __restrict__ sins) {
    int i = blockIdx.x * blockDim.x + threadIdx.x;
    if (i >= SEQ * FREQS) return;
    int s = i >> 8;
    int f = i & 255;
    double e = -(double)((f >> 1) << 1) / (double)FREQS;
    double invf = pow(10000.0, e);
    double ang = (double)s * invf;
    double v = (f & 1) ? cos(ang) : sin(ang);
    sins[i] = (float)(1.4142135623730951 * v);
}

// ---------------------------------------------------------------------------
// fp32 tiled GEMM with templated epilogue.
// EPI 0: C = acc*alpha + bias  (fp32, out projection)
// EPI 1: QKV split -> bf16 Q[b,n,s,h] (x0.125, +bias), K[b,n,s,h], Vt[b,n,h,s]
// EPI 2: embT -> bf16 embT[n,d,h]
// ---------------------------------------------------------------------------
#define BM 64
#define BN 64
#define BK 16

template<int EPI>
__global__ __launch_bounds__(256) void gemm_kernel(
    const float* __restrict__ A, const float* __restrict__ B,
    float* __restrict__ C, bf16* __restrict__ qout, bf16* __restrict__ kout,
    bf16* __restrict__ vout, int M, int N, int K, float alpha,
    const float* __restrict__ bias)
{
    __shared__ __align__(16) float As[BK][BM + 1];
    __shared__ __align__(16) float Bs[BK][BN];

    const int t  = threadIdx.x;
    const int m0 = blockIdx.y * BM;
    const int n0 = blockIdx.x * BN;
    const int tx = t & 15;
    const int ty = t >> 4;

    const int ar  = t >> 2;
    const int ac4 = (t & 3) * 4;
    const int br  = t >> 4;
    const int bc4 = (t & 15) * 4;

    float acc[4][4] = {};

    for (int k0 = 0; k0 < K; k0 += BK) {
        float4 av = *(const float4*)(A + (size_t)(m0 + ar) * K + k0 + ac4);
        As[ac4 + 0][ar] = av.x;
        As[ac4 + 1][ar] = av.y;
        As[ac4 + 2][ar] = av.z;
        As[ac4 + 3][ar] = av.w;
        float4 bv = *(const float4*)(B + (size_t)(k0 + br) * N + n0 + bc4);
        *(float4*)(&Bs[br][bc4]) = bv;
        __syncthreads();

#pragma unroll
        for (int kk = 0; kk < BK; kk++) {
            float a[4], b[4];
#pragma unroll
            for (int i = 0; i < 4; i++) a[i] = As[kk][ty * 4 + i];
#pragma unroll
            for (int j = 0; j < 4; j++) b[j] = Bs[kk][tx * 4 + j];
#pragma unroll
            for (int i = 0; i < 4; i++)
#pragma unroll
                for (int j = 0; j < 4; j++) acc[i][j] += a[i] * b[j];
        }
        __syncthreads();
    }

    if constexpr (EPI == 0) {
#pragma unroll
        for (int i = 0; i < 4; i++) {
            int row = m0 + ty * 4 + i;
#pragma unroll
            for (int j = 0; j < 4; j++) {
                int col = n0 + tx * 4 + j;
                C[(size_t)row * N + col] = acc[i][j] * alpha + bias[col];
            }
        }
    } else if constexpr (EPI == 1) {
        const int which = n0 >> 10;          // 0=q 1=k 2=v (uniform per block)
        const int n     = (n0 & 1023) >> 6;  // head (uniform per block)
#pragma unroll
        for (int i = 0; i < 4; i++) {
            int row = m0 + ty * 4 + i;
            int bb = row >> 11, s = row & 2047;
            if (which == 0) {
                ushort4 pk;
                float v0 = (acc[i][0] * alpha + bias[(n0 & 1023) + tx * 4 + 0]) * 0.125f;
                float v1 = (acc[i][1] * alpha + bias[(n0 & 1023) + tx * 4 + 1]) * 0.125f;
                float v2 = (acc[i][2] * alpha + bias[(n0 & 1023) + tx * 4 + 2]) * 0.125f;
                float v3 = (acc[i][3] * alpha + bias[(n0 & 1023) + tx * 4 + 3]) * 0.125f;
                pk.x = bf16_bits(v0); pk.y = bf16_bits(v1);
                pk.z = bf16_bits(v2); pk.w = bf16_bits(v3);
                *(ushort4*)((unsigned short*)qout +
                            ((size_t)((bb * 16 + n) * SEQ + s)) * 64 + tx * 4) = pk;
            } else if (which == 1) {
                ushort4 pk;
                pk.x = bf16_bits(acc[i][0] * alpha);
                pk.y = bf16_bits(acc[i][1] * alpha);
                pk.z = bf16_bits(acc[i][2] * alpha);
                pk.w = bf16_bits(acc[i][3] * alpha);
                *(ushort4*)((unsigned short*)kout +
                            ((size_t)((bb * 16 + n) * SEQ + s)) * 64 + tx * 4) = pk;
            } else {
#pragma unroll
                for (int j = 0; j < 4; j++) {
                    int h = tx * 4 + j;
                    vout[((size_t)((bb * 16 + n) * 64 + h)) * SEQ + s] =
                        (bf16)(acc[i][j] * alpha);
                }
            }
        }
    } else {  // EPI == 2 : embT[n][d][h]
        const int n = n0 >> 6;
#pragma unroll
        for (int i = 0; i < 4; i++) {
            int d = m0 + ty * 4 + i;
            ushort4 pk;
            pk.x = bf16_bits(acc[i][0] * alpha);
            pk.y = bf16_bits(acc[i][1] * alpha);
            pk.z = bf16_bits(acc[i][2] * alpha);
            pk.w = bf16_bits(acc[i][3] * alpha);
            *(ushort4*)((unsigned short*)qout +
                        ((size_t)(n * SEQ + d)) * 64 + tx * 4) = pk;
        }
    }
}

// ---------------------------------------------------------------------------
// MFMA flash attention with Transformer-XL relative positions.
// Block: 256 thr = 4 waves; one (b,n) and a 64-row Q tile (wave w: 16 rows).
// Per 64-k tile: stage K, Vt, emb band (128 d rows) in LDS; per wave:
//   content S = Q@K^T (8 mfma), pos band = Q@embBand^T (10 mfma) -> LDS ->
//   diagonal gather, mask, online softmax, P->LDS(bf16), O += P@V (8 mfma).
// ---------------------------------------------------------------------------
__global__ __launch_bounds__(256) void attn_kernel(
    const bf16* __restrict__ Qb, const bf16* __restrict__ Kb,
    const bf16* __restrict__ Vtb, const bf16* __restrict__ Eb,
    float* __restrict__ o)
{
    __shared__ __align__(16) bf16 Ks[64][72];
    __shared__ __align__(16) bf16 Vts[64][72];
    __shared__ __align__(16) bf16 Es[128][72];
    __shared__ __align__(16) bf16 PosS[4][16][80];
    __shared__ __align__(16) bf16 PS[4][16][72];

    const int t    = threadIdx.x;
    const int lane = t & 63;
    const int w    = t >> 6;
    const int quad = lane >> 4;
    const int l16  = lane & 15;

    const int bn = blockIdx.y;
    const int b  = bn >> 4, n = bn & 15;
    const int qb = 31 - (int)blockIdx.x;   // heavy blocks dispatched first
    const int q0 = qb * 64;
    const int qw = q0 + w * 16;

    const size_t sbase = ((size_t)(b * 16 + n)) * SEQ * HSIZE;  // Q/K/Vt base
    const size_t ebase = (size_t)n * SEQ * HSIZE;

    // Q fragments (A-operand layout: row = l16, k = quad*8 + j, two h-halves)
    bf16x8 qf0 = *(const bf16x8*)(Qb + sbase + (size_t)(qw + l16) * 64 + quad * 8);
    bf16x8 qf1 = *(const bf16x8*)(Qb + sbase + (size_t)(qw + l16) * 64 + 32 + quad * 8);

    f32x4 O0 = {0,0,0,0}, O1 = {0,0,0,0}, O2 = {0,0,0,0}, O3 = {0,0,0,0};
    float mr[4] = {-1e30f, -1e30f, -1e30f, -1e30f};
    float lr[4] = {0.f, 0.f, 0.f, 0.f};

    for (int kt = 0; kt <= qb; ++kt) {
        const int k0 = kt * 64;
        __syncthreads();  // previous iteration's LDS reads done

        {   // stage K tile (contiguous 8KB)
            const bf16* src = Kb + sbase + (size_t)k0 * 64;
            int fi = t * 16;
            bf16x8 a0 = *(const bf16x8*)(src + fi);
            bf16x8 a1 = *(const bf16x8*)(src + fi + 8);
            int r = t >> 2, cs = (t & 3) * 16;
            *(bf16x8*)&Ks[r][cs]     = a0;
            *(bf16x8*)&Ks[r][cs + 8] = a1;
        }
        {   // stage Vt tile: rows h, cols k0..k0+63 (global already transposed)
            int h = t >> 2, cs = (t & 3) * 16;
            const bf16* src = Vtb + sbase + (size_t)h * SEQ + k0 + cs;
            bf16x8 a0 = *(const bf16x8*)(src);
            bf16x8 a1 = *(const bf16x8*)(src + 8);
            *(bf16x8*)&Vts[h][cs]     = a0;
            *(bf16x8*)&Vts[h][cs + 8] = a1;
        }
        {   // stage emb band rows d = q0-k0-63 + [0,128)
            int ei = t >> 1, es = (t & 1) * 32;
            int d = q0 - k0 - 63 + ei;
            d = d < 0 ? 0 : (d > SEQ - 1 ? SEQ - 1 : d);
            const bf16* src = Eb + ebase + (size_t)d * 64 + es;
            bf16x8 a0 = *(const bf16x8*)(src);
            bf16x8 a1 = *(const bf16x8*)(src + 8);
            bf16x8 a2 = *(const bf16x8*)(src + 16);
            bf16x8 a3 = *(const bf16x8*)(src + 24);
            *(bf16x8*)&Es[ei][es]      = a0;
            *(bf16x8*)&Es[ei][es + 8]  = a1;
            *(bf16x8*)&Es[ei][es + 16] = a2;
            *(bf16x8*)&Es[ei][es + 24] = a3;
        }
        __syncthreads();

        // --- content scores: 4 col-subtiles ---
        f32x4 S[4];
#pragma unroll
        for (int j = 0; j < 4; ++j) {
            bf16x8 kf0 = *(const bf16x8*)(&Ks[j * 16 + l16][quad * 8]);
            bf16x8 kf1 = *(const bf16x8*)(&Ks[j * 16 + l16][32 + quad * 8]);
            f32x4 acc = {0,0,0,0};
            acc = __builtin_amdgcn_mfma_f32_16x16x32_bf16(qf1, kf1, acc, 0, 0, 0);
            acc = __builtin_amdgcn_mfma_f32_16x16x32_bf16(qf0, kf0, acc, 0, 0, 0);
            S[j] = acc;
        }

        // --- positional band: 5 subtiles covering wave band idx [0,80) ---
#pragma unroll
        for (int jj = 0; jj < 5; ++jj) {
            int i0 = 16 * w + 16 * jj;
            bf16x8 e0 = *(const bf16x8*)(&Es[i0 + l16][quad * 8]);
            bf16x8 e1 = *(const bf16x8*)(&Es[i0 + l16][32 + quad * 8]);
            f32x4 acc = {0,0,0,0};
            acc = __builtin_amdgcn_mfma_f32_16x16x32_bf16(qf1, e1, acc, 0, 0, 0);
            acc = __builtin_amdgcn_mfma_f32_16x16x32_bf16(qf0, e0, acc, 0, 0, 0);
#pragma unroll
            for (int rg = 0; rg < 4; ++rg)
                PosS[w][quad * 4 + rg][16 * jj + l16] = (bf16)acc[rg];
        }

        // --- gather pos diag + mask (same-wave LDS, no barrier needed) ---
#pragma unroll
        for (int j = 0; j < 4; ++j) {
#pragma unroll
            for (int rg = 0; rg < 4; ++rg) {
                int rr = quad * 4 + rg;
                int c  = j * 16 + l16;
                int idx = rr - c + 63;               // in [0,78]
                float sv = S[j][rg] + (float)PosS[w][rr][idx];
                int q = qw + rr, k = k0 + c;
                S[j][rg] = (k <= q) ? sv : -1e9f;
            }
        }

        // --- online softmax (row stats via shfl over 16-lane quad groups) ---
        float alpha[4];
#pragma unroll
        for (int rg = 0; rg < 4; ++rg) {
            float v = fmaxf(fmaxf(S[0][rg], S[1][rg]), fmaxf(S[2][rg], S[3][rg]));
            v = fmaxf(v, __shfl_xor(v, 1));
            v = fmaxf(v, __shfl_xor(v, 2));
            v = fmaxf(v, __shfl_xor(v, 4));
            v = fmaxf(v, __shfl_xor(v, 8));
            float mn = fmaxf(mr[rg], v);
            alpha[rg] = __expf(mr[rg] - mn);
            mr[rg] = mn;
        }
#pragma unroll
        for (int j = 0; j < 4; ++j)
#pragma unroll
            for (int rg = 0; rg < 4; ++rg)
                S[j][rg] = __expf(S[j][rg] - mr[rg]);
#pragma unroll
        for (int rg = 0; rg < 4; ++rg) {
            float s = S[0][rg] + S[1][rg] + S[2][rg] + S[3][rg];
            s += __shfl_xor(s, 1);
            s += __shfl_xor(s, 2);
            s += __shfl_xor(s, 4);
            s += __shfl_xor(s, 8);
            lr[rg] = lr[rg] * alpha[rg] + s;
            O0[rg] *= alpha[rg];
            O1[rg] *= alpha[rg];
            O2[rg] *= alpha[rg];
            O3[rg] *= alpha[rg];
        }

        // --- P -> LDS (bf16) then PV ---
#pragma unroll
        for (int j = 0; j < 4; ++j)
#pragma unroll
            for (int rg = 0; rg < 4; ++rg)
                PS[w][quad * 4 + rg][j * 16 + l16] = (bf16)S[j][rg];

        bf16x8 pa0 = *(const bf16x8*)(&PS[w][l16][quad * 8]);
        bf16x8 pa1 = *(const bf16x8*)(&PS[w][l16][32 + quad * 8]);
        {
            bf16x8 v0 = *(const bf16x8*)(&Vts[0 + l16][quad * 8]);
            bf16x8 v1 = *(const bf16x8*)(&Vts[0 + l16][32 + quad * 8]);
            O0 = __builtin_amdgcn_mfma_f32_16x16x32_bf16(pa1, v1, O0, 0, 0, 0);
            O0 = __builtin_amdgcn_mfma_f32_16x16x32_bf16(pa0, v0, O0, 0, 0, 0);
        }
        {
            bf16x8 v0 = *(const bf16x8*)(&Vts[16 + l16][quad * 8]);
            bf16x8 v1 = *(const bf16x8*)(&Vts[16 + l16][32 + quad * 8]);
            O1 = __builtin_amdgcn_mfma_f32_16x16x32_bf16(pa1, v1, O1, 0, 0, 0);
            O1 = __builtin_amdgcn_mfma_f32_16x16x32_bf16(pa0, v0, O1, 0, 0, 0);
        }
        {
            bf16x8 v0 = *(const bf16x8*)(&Vts[32 + l16][quad * 8]);
            bf16x8 v1 = *(const bf16x8*)(&Vts[32 + l16][32 + quad * 8]);
            O2 = __builtin_amdgcn_mfma_f32_16x16x32_bf16(pa1, v1, O2, 0, 0, 0);
            O2 = __builtin_amdgcn_mfma_f32_16x16x32_bf16(pa0, v0, O2, 0, 0, 0);
        }
        {
            bf16x8 v0 = *(const bf16x8*)(&Vts[48 + l16][quad * 8]);
            bf16x8 v1 = *(const bf16x8*)(&Vts[48 + l16][32 + quad * 8]);
            O3 = __builtin_amdgcn_mfma_f32_16x16x32_bf16(pa1, v1, O3, 0, 0, 0);
            O3 = __builtin_amdgcn_mfma_f32_16x16x32_bf16(pa0, v0, O3, 0, 0, 0);
        }
    }

    // --- epilogue: O /= l, write fp32 o[b][s][n*64+h] ---
#pragma unroll
    for (int rg = 0; rg < 4; ++rg) {
        float inv = 1.0f / lr[rg];
        int q = qw + quad * 4 + rg;
        size_t ro = ((size_t)(b * SEQ + q)) * NH + n * 64;
        o[ro +  0 + l16] = O0[rg] * inv;
        o[ro + 16 + l16] = O1[rg] * inv;
        o[ro + 32 + l16] = O2[rg] * inv;
        o[ro + 48 + l16] = O3[rg] * inv;
    }
}

// ---------------------------------------------------------------------------
extern "C" void kernel_launch(void* const* d_in, const int* in_sizes, int n_in,
                              void* d_out, int out_size, void* d_ws, size_t ws_size,
                              hipStream_t stream) {
    const float* inp        = (const float*)d_in[0];
    const float* qkv_w      = (const float*)d_in[1];
    const float* q_bias     = (const float*)d_in[2];
    const float* positional = (const float*)d_in[3];
    const float* out_kernel = (const float*)d_in[4];
    const float* out_bias   = (const float*)d_in[5];
    float* out = (float*)d_out;

    char* p = (char*)d_ws;
    bf16* qbuf  = (bf16*)p; p += (size_t)BATCH * HEADS * SEQ * HSIZE * 2;  // 8 MB
    bf16* kbuf  = (bf16*)p; p += (size_t)BATCH * HEADS * SEQ * HSIZE * 2;  // 8 MB
    bf16* vtbuf = (bf16*)p; p += (size_t)BATCH * HEADS * SEQ * HSIZE * 2;  // 8 MB
    bf16* embT  = (bf16*)p; p += (size_t)HEADS * SEQ * HSIZE * 2;          // 4 MB
    float* sins = (float*)p; p += (size_t)SEQ * FREQS * 4;                 // 2 MB
    float* ov   = (float*)p; p += (size_t)BATCH * SEQ * NH * 4;            // 16 MB

    const float qkv_scale = (float)pow(3.0 * DMODEL * HSIZE * HEADS, -0.25);
    const float emb_scale = 0.0625f;   // 256^-0.5
    const float out_scale = 0.03125f;  // (1024*1024)^-0.25

    sins_kernel<<<(SEQ * FREQS + 255) / 256, 256, 0, stream>>>(sins);

    // QKV projection -> bf16 Q/K/Vt
    gemm_kernel<1><<<dim3(QKVN / BN, (BATCH * SEQ) / BM), 256, 0, stream>>>(
        inp, qkv_w, nullptr, qbuf, kbuf, vtbuf,
        BATCH * SEQ, QKVN, DMODEL, qkv_scale, q_bias);

    // emb -> bf16 embT[n][d][h]
    gemm_kernel<2><<<dim3(NH / BN, SEQ / BM), 256, 0, stream>>>(
        sins, positional, nullptr, embT, nullptr, nullptr,
        SEQ, NH, FREQS, emb_scale, nullptr);

    // flash attention
    attn_kernel<<<dim3(32, BATCH * HEADS), 256, 0, stream>>>(
        qbuf, kbuf, vtbuf, embT, ov);

    // output projection (fp32)
    gemm_kernel<0><<<dim3(NH / BN, (BATCH * SEQ) / BM), 256, 0, stream>>>(
        ov, out_kernel, out, nullptr, nullptr, nullptr,
        BATCH * SEQ, NH, DMODEL, out_scale, out_bias);
}

// Round 3
// 395.295 us; speedup vs baseline: 14.9336x; 1.9731x over previous
//
#include <hip/hip_runtime.h>
#include <math.h>

#define BATCH 2
#define SEQ 2048
#define DMODEL 1024
#define HEADS 16
#define HSIZE 64
#define FREQS 256
#define NH 1024
#define QKVN 3072

typedef __bf16 bf16;
typedef __bf16 bf16x8 __attribute__((ext_vector_type(8)));
typedef float f32x4 __attribute__((ext_vector_type(4)));

static __device__ __forceinline__ unsigned short bf16_bits(float v) {
    bf16 b = (bf16)v; return __builtin_bit_cast(unsigned short, b);
}

// async global->LDS, 16 bytes per lane; LDS dest must be wave-uniform + lane*16
static __device__ __forceinline__ void gload16(const void* g, void* l) {
    __builtin_amdgcn_global_load_lds(
        (const __attribute__((address_space(1))) unsigned int*)g,
        (__attribute__((address_space(3))) unsigned int*)l, 16, 0, 0);
}

// ---------------------------------------------------------------------------
// Sinusoid table (fp64 to match numpy) -> bf16 [SEQ][FREQS]
// ---------------------------------------------------------------------------
__global__ void sins_kernel(bf16* __restrict__ sins) {
    int i = blockIdx.x * blockDim.x + threadIdx.x;
    int s = i >> 8;
    int f = i & 255;
    double e = -(double)((f >> 1) << 1) / (double)FREQS;
    double invf = pow(10000.0, e);
    double ang = (double)s * invf;
    double v = (f & 1) ? cos(ang) : sin(ang);
    sins[i] = (bf16)(float)(1.4142135623730951 * v);
}

// ---------------------------------------------------------------------------
// fp32 -> bf16 elementwise cast (vectorized), n4 = elements/4
// ---------------------------------------------------------------------------
__global__ void cast_bf16(const float* __restrict__ src, bf16* __restrict__ dst, int n4) {
    int i = blockIdx.x * blockDim.x + threadIdx.x;
    if (i >= n4) return;
    float4 v = ((const float4*)src)[i];
    ushort4 o;
    o.x = bf16_bits(v.x); o.y = bf16_bits(v.y);
    o.z = bf16_bits(v.z); o.w = bf16_bits(v.w);
    ((ushort4*)dst)[i] = o;
}

// ---------------------------------------------------------------------------
// fp32 [R][C] -> bf16 [C][R] transpose+cast, 32x32 LDS tiles, block=256
// ---------------------------------------------------------------------------
__global__ __launch_bounds__(256) void transpose_cast(
    const float* __restrict__ src, bf16* __restrict__ dst, int R, int C)
{
    __shared__ float tile[32][33];
    const int tx = threadIdx.x & 31, ty = threadIdx.x >> 5;  // ty 0..7
    const int c0 = blockIdx.x * 32, r0 = blockIdx.y * 32;
#pragma unroll
    for (int i = 0; i < 4; i++)
        tile[ty + i * 8][tx] = src[(size_t)(r0 + ty + i * 8) * C + c0 + tx];
    __syncthreads();
#pragma unroll
    for (int i = 0; i < 4; i++)
        dst[(size_t)(c0 + ty + i * 8) * R + r0 + tx] = (bf16)tile[tx][ty + i * 8];
}

// ---------------------------------------------------------------------------
// bf16 MFMA GEMM: C[M][N] = A[M][K] @ Bt[N][K]^T, 128x128 tile, BK=32,
// 4 waves each 64x64 (4x4 tiles of 16x16x32). global_load_lds staging with
// XOR chunk swizzle (2-way LDS bank aliasing = free).
// EPI 0: out-proj: fp32 out = acc*alpha + bias[col], N=1024
// EPI 1: QK: bf16 ob0=Q[bn][s][h] ((acc*alpha+bias)*0.125), ob1=K (acc*alpha)
// EPI 2: V with swapped operands -> Vt[bn][h][s] = acc*alpha
// EPI 3: embT[head][d][h] = acc*alpha
// ---------------------------------------------------------------------------
template<int EPI>
__global__ __launch_bounds__(256) void mfma_gemm(
    const bf16* __restrict__ A, const bf16* __restrict__ Bt,
    int K, int n_off, float alpha, const float* __restrict__ bias,
    float* __restrict__ outf, bf16* __restrict__ ob0, bf16* __restrict__ ob1)
{
    __shared__ __align__(16) bf16 Atile[128 * 32];
    __shared__ __align__(16) bf16 Btile[128 * 32];

    const int t    = threadIdx.x;
    const int lane = t & 63;
    const int w    = t >> 6;
    const int quad = lane >> 4;
    const int l16  = lane & 15;
    const int m0   = blockIdx.y * 128;
    const int n0   = blockIdx.x * 128;
    const int wm   = (w >> 1) * 64;
    const int wn   = (w & 1) * 64;

    // staging coords: 16B chunk p -> row p>>2, phys chunk p&3 holds logical
    // k-chunk (p&3) ^ ((row>>1)&3)
    const int rS  = t >> 2;
    const int cS  = (t & 3) ^ ((rS >> 1) & 3);
    const bf16* ag0 = A  + (size_t)(m0 + rS) * K + cS * 8;
    const bf16* ag1 = A  + (size_t)(m0 + rS + 64) * K + cS * 8;
    const bf16* bg0 = Bt + (size_t)(n0 + rS) * K + cS * 8;
    const bf16* bg1 = Bt + (size_t)(n0 + rS + 64) * K + cS * 8;
    bf16* al0 = Atile + t * 8;
    bf16* al1 = Atile + (t + 256) * 8;
    bf16* bl0 = Btile + t * 8;
    bf16* bl1 = Btile + (t + 256) * 8;

    // fragment LDS offsets (constant across K loop)
    int aoff[4], boff[4];
#pragma unroll
    for (int mi = 0; mi < 4; ++mi) {
        int r = wm + mi * 16 + l16;
        aoff[mi] = r * 32 + ((quad ^ ((r >> 1) & 3)) * 8);
    }
#pragma unroll
    for (int ni = 0; ni < 4; ++ni) {
        int r = wn + ni * 16 + l16;
        boff[ni] = r * 32 + ((quad ^ ((r >> 1) & 3)) * 8);
    }

    f32x4 acc[4][4] = {};

    for (int kk = 0; kk < K; kk += 32) {
        __syncthreads();
        gload16(ag0, al0); gload16(ag1, al1);
        gload16(bg0, bl0); gload16(bg1, bl1);
        ag0 += 32; ag1 += 32; bg0 += 32; bg1 += 32;
        __syncthreads();

        bf16x8 af[4], bfr[4];
#pragma unroll
        for (int mi = 0; mi < 4; ++mi) af[mi] = *(const bf16x8*)(Atile + aoff[mi]);
#pragma unroll
        for (int ni = 0; ni < 4; ++ni) bfr[ni] = *(const bf16x8*)(Btile + boff[ni]);

#pragma unroll
        for (int mi = 0; mi < 4; ++mi)
#pragma unroll
            for (int ni = 0; ni < 4; ++ni) {
                if constexpr (EPI == 2)
                    acc[mi][ni] = __builtin_amdgcn_mfma_f32_16x16x32_bf16(
                        bfr[ni], af[mi], acc[mi][ni], 0, 0, 0);
                else
                    acc[mi][ni] = __builtin_amdgcn_mfma_f32_16x16x32_bf16(
                        af[mi], bfr[ni], acc[mi][ni], 0, 0, 0);
            }
    }

    if constexpr (EPI == 0) {
#pragma unroll
        for (int mi = 0; mi < 4; ++mi)
#pragma unroll
            for (int ni = 0; ni < 4; ++ni) {
                int col = n0 + wn + ni * 16 + l16;
                float bb = bias[col];
#pragma unroll
                for (int rg = 0; rg < 4; ++rg) {
                    int row = m0 + wm + mi * 16 + quad * 4 + rg;
                    outf[(size_t)row * NH + col] = acc[mi][ni][rg] * alpha + bb;
                }
            }
    } else if constexpr (EPI == 1) {
        const int which = (n0 >= 1024);
#pragma unroll
        for (int mi = 0; mi < 4; ++mi)
#pragma unroll
            for (int ni = 0; ni < 4; ++ni) {
                int cg   = (n0 + wn + ni * 16 + l16) & 1023;
                int head = cg >> 6, h = cg & 63;
                float qb = which ? 0.0f : bias[cg];
#pragma unroll
                for (int rg = 0; rg < 4; ++rg) {
                    int row = m0 + wm + mi * 16 + quad * 4 + rg;
                    int b = row >> 11, s = row & 2047;
                    size_t idx = ((size_t)((b * 16 + head) * SEQ + s)) * 64 + h;
                    float v = acc[mi][ni][rg] * alpha;
                    if (which) ob1[idx] = (bf16)v;
                    else       ob0[idx] = (bf16)((v + qb) * 0.125f);
                }
            }
    } else if constexpr (EPI == 2) {
#pragma unroll
        for (int mi = 0; mi < 4; ++mi)
#pragma unroll
            for (int ni = 0; ni < 4; ++ni) {
                int mcol = m0 + wm + mi * 16 + l16;
                int b = mcol >> 11, s = mcol & 2047;
#pragma unroll
                for (int rg = 0; rg < 4; ++rg) {
                    int hg = n_off + n0 + wn + ni * 16 + quad * 4 + rg;
                    int head = (hg & 1023) >> 6, h = hg & 63;
                    ob0[((size_t)((b * 16 + head) * 64 + h)) * SEQ + s] =
                        (bf16)(acc[mi][ni][rg] * alpha);
                }
            }
    } else {  // EPI == 3: embT[head][d][h]
#pragma unroll
        for (int mi = 0; mi < 4; ++mi)
#pragma unroll
            for (int ni = 0; ni < 4; ++ni) {
                int col = n0 + wn + ni * 16 + l16;
                int head = col >> 6, h = col & 63;
#pragma unroll
                for (int rg = 0; rg < 4; ++rg) {
                    int d = m0 + wm + mi * 16 + quad * 4 + rg;
                    ob0[((size_t)(head * SEQ + d)) * 64 + h] =
                        (bf16)(acc[mi][ni][rg] * alpha);
                }
            }
    }
}

// ---------------------------------------------------------------------------
// MFMA flash attention (unchanged from round 2 except bf16 output)
// ---------------------------------------------------------------------------
__global__ __launch_bounds__(256) void attn_kernel(
    const bf16* __restrict__ Qb, const bf16* __restrict__ Kb,
    const bf16* __restrict__ Vtb, const bf16* __restrict__ Eb,
    bf16* __restrict__ o)
{
    __shared__ __align__(16) bf16 Ks[64][72];
    __shared__ __align__(16) bf16 Vts[64][72];
    __shared__ __align__(16) bf16 Es[128][72];
    __shared__ __align__(16) bf16 PosS[4][16][80];
    __shared__ __align__(16) bf16 PS[4][16][72];

    const int t    = threadIdx.x;
    const int lane = t & 63;
    const int w    = t >> 6;
    const int quad = lane >> 4;
    const int l16  = lane & 15;

    const int bn = blockIdx.y;
    const int b  = bn >> 4, n = bn & 15;
    const int qb = 31 - (int)blockIdx.x;
    const int q0 = qb * 64;
    const int qw = q0 + w * 16;

    const size_t sbase = ((size_t)(b * 16 + n)) * SEQ * HSIZE;
    const size_t ebase = (size_t)n * SEQ * HSIZE;

    bf16x8 qf0 = *(const bf16x8*)(Qb + sbase + (size_t)(qw + l16) * 64 + quad * 8);
    bf16x8 qf1 = *(const bf16x8*)(Qb + sbase + (size_t)(qw + l16) * 64 + 32 + quad * 8);

    f32x4 O0 = {0,0,0,0}, O1 = {0,0,0,0}, O2 = {0,0,0,0}, O3 = {0,0,0,0};
    float mr[4] = {-1e30f, -1e30f, -1e30f, -1e30f};
    float lr[4] = {0.f, 0.f, 0.f, 0.f};

    for (int kt = 0; kt <= qb; ++kt) {
        const int k0 = kt * 64;
        __syncthreads();

        {
            const bf16* src = Kb + sbase + (size_t)k0 * 64;
            int fi = t * 16;
            bf16x8 a0 = *(const bf16x8*)(src + fi);
            bf16x8 a1 = *(const bf16x8*)(src + fi + 8);
            int r = t >> 2, cs = (t & 3) * 16;
            *(bf16x8*)&Ks[r][cs]     = a0;
            *(bf16x8*)&Ks[r][cs + 8] = a1;
        }
        {
            int h = t >> 2, cs = (t & 3) * 16;
            const bf16* src = Vtb + sbase + (size_t)h * SEQ + k0 + cs;
            bf16x8 a0 = *(const bf16x8*)(src);
            bf16x8 a1 = *(const bf16x8*)(src + 8);
            *(bf16x8*)&Vts[h][cs]     = a0;
            *(bf16x8*)&Vts[h][cs + 8] = a1;
        }
        {
            int ei = t >> 1, es = (t & 1) * 32;
            int d = q0 - k0 - 63 + ei;
            d = d < 0 ? 0 : (d > SEQ - 1 ? SEQ - 1 : d);
            const bf16* src = Eb + ebase + (size_t)d * 64 + es;
            bf16x8 a0 = *(const bf16x8*)(src);
            bf16x8 a1 = *(const bf16x8*)(src + 8);
            bf16x8 a2 = *(const bf16x8*)(src + 16);
            bf16x8 a3 = *(const bf16x8*)(src + 24);
            *(bf16x8*)&Es[ei][es]      = a0;
            *(bf16x8*)&Es[ei][es + 8]  = a1;
            *(bf16x8*)&Es[ei][es + 16] = a2;
            *(bf16x8*)&Es[ei][es + 24] = a3;
        }
        __syncthreads();

        f32x4 S[4];
#pragma unroll
        for (int j = 0; j < 4; ++j) {
            bf16x8 kf0 = *(const bf16x8*)(&Ks[j * 16 + l16][quad * 8]);
            bf16x8 kf1 = *(const bf16x8*)(&Ks[j * 16 + l16][32 + quad * 8]);
            f32x4 acc = {0,0,0,0};
            acc = __builtin_amdgcn_mfma_f32_16x16x32_bf16(qf1, kf1, acc, 0, 0, 0);
            acc = __builtin_amdgcn_mfma_f32_16x16x32_bf16(qf0, kf0, acc, 0, 0, 0);
            S[j] = acc;
        }

#pragma unroll
        for (int jj = 0; jj < 5; ++jj) {
            int i0 = 16 * w + 16 * jj;
            bf16x8 e0 = *(const bf16x8*)(&Es[i0 + l16][quad * 8]);
            bf16x8 e1 = *(const bf16x8*)(&Es[i0 + l16][32 + quad * 8]);
            f32x4 acc = {0,0,0,0};
            acc = __builtin_amdgcn_mfma_f32_16x16x32_bf16(qf1, e1, acc, 0, 0, 0);
            acc = __builtin_amdgcn_mfma_f32_16x16x32_bf16(qf0, e0, acc, 0, 0, 0);
#pragma unroll
            for (int rg = 0; rg < 4; ++rg)
                PosS[w][quad * 4 + rg][16 * jj + l16] = (bf16)acc[rg];
        }

#pragma unroll
        for (int j = 0; j < 4; ++j) {
#pragma unroll
            for (int rg = 0; rg < 4; ++rg) {
                int rr = quad * 4 + rg;
                int c  = j * 16 + l16;
                int idx = rr - c + 63;
                float sv = S[j][rg] + (float)PosS[w][rr][idx];
                int q = qw + rr, k = k0 + c;
                S[j][rg] = (k <= q) ? sv : -1e9f;
            }
        }

        float alpha[4];
#pragma unroll
        for (int rg = 0; rg < 4; ++rg) {
            float v = fmaxf(fmaxf(S[0][rg], S[1][rg]), fmaxf(S[2][rg], S[3][rg]));
            v = fmaxf(v, __shfl_xor(v, 1));
            v = fmaxf(v, __shfl_xor(v, 2));
            v = fmaxf(v, __shfl_xor(v, 4));
            v = fmaxf(v, __shfl_xor(v, 8));
            float mn = fmaxf(mr[rg], v);
            alpha[rg] = __expf(mr[rg] - mn);
            mr[rg] = mn;
        }
#pragma unroll
        for (int j = 0; j < 4; ++j)
#pragma unroll
            for (int rg = 0; rg < 4; ++rg)
                S[j][rg] = __expf(S[j][rg] - mr[rg]);
#pragma unroll
        for (int rg = 0; rg < 4; ++rg) {
            float s = S[0][rg] + S[1][rg] + S[2][rg] + S[3][rg];
            s += __shfl_xor(s, 1);
            s += __shfl_xor(s, 2);
            s += __shfl_xor(s, 4);
            s += __shfl_xor(s, 8);
            lr[rg] = lr[rg] * alpha[rg] + s;
            O0[rg] *= alpha[rg];
            O1[rg] *= alpha[rg];
            O2[rg] *= alpha[rg];
            O3[rg] *= alpha[rg];
        }

#pragma unroll
        for (int j = 0; j < 4; ++j)
#pragma unroll
            for (int rg = 0; rg < 4; ++rg)
                PS[w][quad * 4 + rg][j * 16 + l16] = (bf16)S[j][rg];

        bf16x8 pa0 = *(const bf16x8*)(&PS[w][l16][quad * 8]);
        bf16x8 pa1 = *(const bf16x8*)(&PS[w][l16][32 + quad * 8]);
        {
            bf16x8 v0 = *(const bf16x8*)(&Vts[0 + l16][quad * 8]);
            bf16x8 v1 = *(const bf16x8*)(&Vts[0 + l16][32 + quad * 8]);
            O0 = __builtin_amdgcn_mfma_f32_16x16x32_bf16(pa1, v1, O0, 0, 0, 0);
            O0 = __builtin_amdgcn_mfma_f32_16x16x32_bf16(pa0, v0, O0, 0, 0, 0);
        }
        {
            bf16x8 v0 = *(const bf16x8*)(&Vts[16 + l16][quad * 8]);
            bf16x8 v1 = *(const bf16x8*)(&Vts[16 + l16][32 + quad * 8]);
            O1 = __builtin_amdgcn_mfma_f32_16x16x32_bf16(pa1, v1, O1, 0, 0, 0);
            O1 = __builtin_amdgcn_mfma_f32_16x16x32_bf16(pa0, v0, O1, 0, 0, 0);
        }
        {
            bf16x8 v0 = *(const bf16x8*)(&Vts[32 + l16][quad * 8]);
            bf16x8 v1 = *(const bf16x8*)(&Vts[32 + l16][32 + quad * 8]);
            O2 = __builtin_amdgcn_mfma_f32_16x16x32_bf16(pa1, v1, O2, 0, 0, 0);
            O2 = __builtin_amdgcn_mfma_f32_16x16x32_bf16(pa0, v0, O2, 0, 0, 0);
        }
        {
            bf16x8 v0 = *(const bf16x8*)(&Vts[48 + l16][quad * 8]);
            bf16x8 v1 = *(const bf16x8*)(&Vts[48 + l16][32 + quad * 8]);
            O3 = __builtin_amdgcn_mfma_f32_16x16x32_bf16(pa1, v1, O3, 0, 0, 0);
            O3 = __builtin_amdgcn_mfma_f32_16x16x32_bf16(pa0, v0, O3, 0, 0, 0);
        }
    }

#pragma unroll
    for (int rg = 0; rg < 4; ++rg) {
        float inv = 1.0f / lr[rg];
        int q = qw + quad * 4 + rg;
        size_t ro = ((size_t)(b * SEQ + q)) * NH + n * 64;
        o[ro +  0 + l16] = (bf16)(O0[rg] * inv);
        o[ro + 16 + l16] = (bf16)(O1[rg] * inv);
        o[ro + 32 + l16] = (bf16)(O2[rg] * inv);
        o[ro + 48 + l16] = (bf16)(O3[rg] * inv);
    }
}

// ---------------------------------------------------------------------------
extern "C" void kernel_launch(void* const* d_in, const int* in_sizes, int n_in,
                              void* d_out, int out_size, void* d_ws, size_t ws_size,
                              hipStream_t stream) {
    const float* inp        = (const float*)d_in[0];
    const float* qkv_w      = (const float*)d_in[1];
    const float* q_bias     = (const float*)d_in[2];
    const float* positional = (const float*)d_in[3];
    const float* out_kernel = (const float*)d_in[4];
    const float* out_bias   = (const float*)d_in[5];

    char* p = (char*)d_ws;
    auto alloc = [&](size_t bytes) {
        char* q = p; p += (bytes + 255) & ~(size_t)255; return q;
    };
    bf16* qbuf    = (bf16*)alloc((size_t)BATCH * HEADS * SEQ * HSIZE * 2);
    bf16* kbuf    = (bf16*)alloc((size_t)BATCH * HEADS * SEQ * HSIZE * 2);
    bf16* vtbuf   = (bf16*)alloc((size_t)BATCH * HEADS * SEQ * HSIZE * 2);
    bf16* embT    = (bf16*)alloc((size_t)HEADS * SEQ * HSIZE * 2);
    bf16* sins_bf = (bf16*)alloc((size_t)SEQ * FREQS * 2);
    bf16* obuf    = (bf16*)alloc((size_t)BATCH * SEQ * NH * 2);
    bf16* a_bf    = (bf16*)alloc((size_t)BATCH * SEQ * DMODEL * 2);
    bf16* wt_qkv  = (bf16*)alloc((size_t)QKVN * DMODEL * 2);
    bf16* wt_out  = (bf16*)alloc((size_t)NH * DMODEL * 2);
    bf16* wt_pos  = (bf16*)alloc((size_t)NH * FREQS * 2);

    const float qkv_scale = (float)pow(3.0 * DMODEL * HSIZE * HEADS, -0.25);
    const float emb_scale = 0.0625f;   // 256^-0.5
    const float out_scale = 0.03125f;  // (1024*1024)^-0.25

    // prep: casts + transposes + sins
    cast_bf16<<<(BATCH * SEQ * DMODEL / 4 + 255) / 256, 256, 0, stream>>>(
        inp, a_bf, BATCH * SEQ * DMODEL / 4);
    transpose_cast<<<dim3(QKVN / 32, DMODEL / 32), 256, 0, stream>>>(
        qkv_w, wt_qkv, DMODEL, QKVN);
    transpose_cast<<<dim3(NH / 32, DMODEL / 32), 256, 0, stream>>>(
        out_kernel, wt_out, DMODEL, NH);
    transpose_cast<<<dim3(NH / 32, FREQS / 32), 256, 0, stream>>>(
        positional, wt_pos, FREQS, NH);
    sins_kernel<<<SEQ * FREQS / 256, 256, 0, stream>>>(sins_bf);

    // QK projection (cols 0..2047 of qkv)
    mfma_gemm<1><<<dim3(16, 32), 256, 0, stream>>>(
        a_bf, wt_qkv, DMODEL, 0, qkv_scale, q_bias, nullptr, qbuf, kbuf);
    // V projection (cols 2048..3071), swapped operands -> Vt directly
    mfma_gemm<2><<<dim3(8, 32), 256, 0, stream>>>(
        a_bf, wt_qkv + (size_t)2048 * DMODEL, DMODEL, 2048, qkv_scale, nullptr,
        nullptr, vtbuf, nullptr);
    // emb -> embT[head][d][h]
    mfma_gemm<3><<<dim3(8, 16), 256, 0, stream>>>(
        sins_bf, wt_pos, FREQS, 0, emb_scale, nullptr, nullptr, embT, nullptr);

    // flash attention -> bf16 o
    attn_kernel<<<dim3(32, BATCH * HEADS), 256, 0, stream>>>(
        qbuf, kbuf, vtbuf, embT, obuf);

    // output projection (fp32 out)
    mfma_gemm<0><<<dim3(8, 32), 256, 0, stream>>>(
        obuf, wt_out, DMODEL, 0, out_scale, out_bias, (float*)d_out,
        nullptr, nullptr);
}

// Round 4
// 318.366 us; speedup vs baseline: 18.5421x; 1.2416x over previous
//
#include <hip/hip_runtime.h>
#include <math.h>

#define BATCH 2
#define SEQ 2048
#define DMODEL 1024
#define HEADS 16
#define HSIZE 64
#define FREQS 256
#define NH 1024
#define QKVN 3072

typedef __bf16 bf16;
typedef __bf16 bf16x8 __attribute__((ext_vector_type(8)));
typedef float f32x4 __attribute__((ext_vector_type(4)));

static __device__ __forceinline__ unsigned short bf16_bits(float v) {
    bf16 b = (bf16)v; return __builtin_bit_cast(unsigned short, b);
}

// async global->LDS, 16 bytes per lane; LDS dest = wave-uniform base + lane*16
static __device__ __forceinline__ void gload16(const void* g, void* l) {
    __builtin_amdgcn_global_load_lds(
        (const __attribute__((address_space(1))) unsigned int*)g,
        (__attribute__((address_space(3))) unsigned int*)l, 16, 0, 0);
}

// ---------------------------------------------------------------------------
// Sinusoid table (fp64 to match numpy) -> bf16 [SEQ][FREQS]
// ---------------------------------------------------------------------------
__global__ void sins_kernel(bf16* __restrict__ sins) {
    int i = blockIdx.x * blockDim.x + threadIdx.x;
    int s = i >> 8;
    int f = i & 255;
    double e = -(double)((f >> 1) << 1) / (double)FREQS;
    double invf = pow(10000.0, e);
    double ang = (double)s * invf;
    double v = (f & 1) ? cos(ang) : sin(ang);
    sins[i] = (bf16)(float)(1.4142135623730951 * v);
}

// ---------------------------------------------------------------------------
// fp32 -> bf16 elementwise cast (vectorized), n4 = elements/4
// ---------------------------------------------------------------------------
__global__ void cast_bf16(const float* __restrict__ src, bf16* __restrict__ dst, int n4) {
    int i = blockIdx.x * blockDim.x + threadIdx.x;
    if (i >= n4) return;
    float4 v = ((const float4*)src)[i];
    ushort4 o;
    o.x = bf16_bits(v.x); o.y = bf16_bits(v.y);
    o.z = bf16_bits(v.z); o.w = bf16_bits(v.w);
    ((ushort4*)dst)[i] = o;
}

// ---------------------------------------------------------------------------
// fp32 [R][C] -> bf16 [C][R] transpose+cast, 32x32 LDS tiles, block=256
// ---------------------------------------------------------------------------
__global__ __launch_bounds__(256) void transpose_cast(
    const float* __restrict__ src, bf16* __restrict__ dst, int R, int C)
{
    __shared__ float tile[32][33];
    const int tx = threadIdx.x & 31, ty = threadIdx.x >> 5;  // ty 0..7
    const int c0 = blockIdx.x * 32, r0 = blockIdx.y * 32;
#pragma unroll
    for (int i = 0; i < 4; i++)
        tile[ty + i * 8][tx] = src[(size_t)(r0 + ty + i * 8) * C + c0 + tx];
    __syncthreads();
#pragma unroll
    for (int i = 0; i < 4; i++)
        dst[(size_t)(c0 + ty + i * 8) * R + r0 + tx] = (bf16)tile[tx][ty + i * 8];
}

// ---------------------------------------------------------------------------
// bf16 MFMA GEMM: C[M][N] = A[M][K] @ Bt[N][K]^T, 128x128 tile, BK=32.
// EPI 0: out-proj fp32 = acc*alpha + bias[col]
// EPI 1: QK: ob0 = Q[bn][s][h] plain ((acc*alpha+bias)*0.125);
//        ob1 = K[bn][s][h^((s&7)<<3)]  (chunk-swizzled for attn LDS)
// EPI 2: V swapped operands -> Vt[bn][h][s^((h&7)<<3)]
// EPI 3: embT[head][d][h^(((d+63)&7)<<3)]
// ---------------------------------------------------------------------------
template<int EPI>
__global__ __launch_bounds__(256) void mfma_gemm(
    const bf16* __restrict__ A, const bf16* __restrict__ Bt,
    int K, int n_off, float alpha, const float* __restrict__ bias,
    float* __restrict__ outf, bf16* __restrict__ ob0, bf16* __restrict__ ob1)
{
    __shared__ __align__(16) bf16 Atile[128 * 32];
    __shared__ __align__(16) bf16 Btile[128 * 32];

    const int t    = threadIdx.x;
    const int lane = t & 63;
    const int w    = t >> 6;
    const int quad = lane >> 4;
    const int l16  = lane & 15;
    const int m0   = blockIdx.y * 128;
    const int n0   = blockIdx.x * 128;
    const int wm   = (w >> 1) * 64;
    const int wn   = (w & 1) * 64;

    const int rS  = t >> 2;
    const int cS  = (t & 3) ^ ((rS >> 1) & 3);
    const bf16* ag0 = A  + (size_t)(m0 + rS) * K + cS * 8;
    const bf16* ag1 = A  + (size_t)(m0 + rS + 64) * K + cS * 8;
    const bf16* bg0 = Bt + (size_t)(n0 + rS) * K + cS * 8;
    const bf16* bg1 = Bt + (size_t)(n0 + rS + 64) * K + cS * 8;
    bf16* al0 = Atile + t * 8;
    bf16* al1 = Atile + (t + 256) * 8;
    bf16* bl0 = Btile + t * 8;
    bf16* bl1 = Btile + (t + 256) * 8;

    int aoff[4], boff[4];
#pragma unroll
    for (int mi = 0; mi < 4; ++mi) {
        int r = wm + mi * 16 + l16;
        aoff[mi] = r * 32 + ((quad ^ ((r >> 1) & 3)) * 8);
    }
#pragma unroll
    for (int ni = 0; ni < 4; ++ni) {
        int r = wn + ni * 16 + l16;
        boff[ni] = r * 32 + ((quad ^ ((r >> 1) & 3)) * 8);
    }

    f32x4 acc[4][4] = {};

    for (int kk = 0; kk < K; kk += 32) {
        __syncthreads();
        gload16(ag0, al0); gload16(ag1, al1);
        gload16(bg0, bl0); gload16(bg1, bl1);
        ag0 += 32; ag1 += 32; bg0 += 32; bg1 += 32;
        __syncthreads();

        bf16x8 af[4], bfr[4];
#pragma unroll
        for (int mi = 0; mi < 4; ++mi) af[mi] = *(const bf16x8*)(Atile + aoff[mi]);
#pragma unroll
        for (int ni = 0; ni < 4; ++ni) bfr[ni] = *(const bf16x8*)(Btile + boff[ni]);

#pragma unroll
        for (int mi = 0; mi < 4; ++mi)
#pragma unroll
            for (int ni = 0; ni < 4; ++ni) {
                if constexpr (EPI == 2)
                    acc[mi][ni] = __builtin_amdgcn_mfma_f32_16x16x32_bf16(
                        bfr[ni], af[mi], acc[mi][ni], 0, 0, 0);
                else
                    acc[mi][ni] = __builtin_amdgcn_mfma_f32_16x16x32_bf16(
                        af[mi], bfr[ni], acc[mi][ni], 0, 0, 0);
            }
    }

    if constexpr (EPI == 0) {
#pragma unroll
        for (int mi = 0; mi < 4; ++mi)
#pragma unroll
            for (int ni = 0; ni < 4; ++ni) {
                int col = n0 + wn + ni * 16 + l16;
                float bb = bias[col];
#pragma unroll
                for (int rg = 0; rg < 4; ++rg) {
                    int row = m0 + wm + mi * 16 + quad * 4 + rg;
                    outf[(size_t)row * NH + col] = acc[mi][ni][rg] * alpha + bb;
                }
            }
    } else if constexpr (EPI == 1) {
        const int which = (n0 >= 1024);
#pragma unroll
        for (int mi = 0; mi < 4; ++mi)
#pragma unroll
            for (int ni = 0; ni < 4; ++ni) {
                int cg   = (n0 + wn + ni * 16 + l16) & 1023;
                int head = cg >> 6, h = cg & 63;
                float qbv = which ? 0.0f : bias[cg];
#pragma unroll
                for (int rg = 0; rg < 4; ++rg) {
                    int row = m0 + wm + mi * 16 + quad * 4 + rg;
                    int bb = row >> 11, s = row & 2047;
                    float v = acc[mi][ni][rg] * alpha;
                    if (which) {
                        int hs = h ^ ((s & 7) << 3);
                        ob1[((size_t)((bb * 16 + head) * SEQ + s)) * 64 + hs] = (bf16)v;
                    } else {
                        ob0[((size_t)((bb * 16 + head) * SEQ + s)) * 64 + h] =
                            (bf16)((v + qbv) * 0.125f);
                    }
                }
            }
    } else if constexpr (EPI == 2) {
#pragma unroll
        for (int mi = 0; mi < 4; ++mi)
#pragma unroll
            for (int ni = 0; ni < 4; ++ni) {
                int mcol = m0 + wm + mi * 16 + l16;
                int bb = mcol >> 11, s = mcol & 2047;
#pragma unroll
                for (int rg = 0; rg < 4; ++rg) {
                    int hg = n_off + n0 + wn + ni * 16 + quad * 4 + rg;
                    int head = (hg & 1023) >> 6, h = hg & 63;
                    int ss = s ^ ((h & 7) << 3);
                    ob0[((size_t)((bb * 16 + head) * 64 + h)) * SEQ + ss] =
                        (bf16)(acc[mi][ni][rg] * alpha);
                }
            }
    } else {  // EPI == 3: embT[head][d][h'] chunk-swizzled by (d+63)&7
#pragma unroll
        for (int mi = 0; mi < 4; ++mi)
#pragma unroll
            for (int ni = 0; ni < 4; ++ni) {
                int col = n0 + wn + ni * 16 + l16;
                int head = col >> 6, h = col & 63;
#pragma unroll
                for (int rg = 0; rg < 4; ++rg) {
                    int d = m0 + wm + mi * 16 + quad * 4 + rg;
                    int hs = h ^ (((d + 63) & 7) << 3);
                    ob0[((size_t)(head * SEQ + d)) * 64 + hs] =
                        (bf16)(acc[mi][ni][rg] * alpha);
                }
            }
    }
}

// ---------------------------------------------------------------------------
// MFMA flash attention v4: no-max softmax, ds_permute pos gather,
// global_load_lds staging from pre-swizzled K/Vt/embT, Es ring buffer.
// Block: 256 thr = 4 waves; one (b,n), 64-q tile (wave w: 16 rows).
// ---------------------------------------------------------------------------
__global__ __launch_bounds__(256) void attn_kernel(
    const bf16* __restrict__ Qb, const bf16* __restrict__ Kb,
    const bf16* __restrict__ Vtb, const bf16* __restrict__ Eb,
    bf16* __restrict__ o)
{
    __shared__ __align__(16) bf16 Ks[64 * 64];     // swizzled, pitch 64
    __shared__ __align__(16) bf16 Vts[64 * 64];
    __shared__ __align__(16) bf16 Es[128 * 64];    // ring, phys row = (d+63)&127
    __shared__ __align__(16) bf16 PS[4][16][72];

    const int t    = threadIdx.x;
    const int lane = t & 63;
    const int w    = t >> 6;
    const int quad = lane >> 4;
    const int l16  = lane & 15;

    const int bn = blockIdx.y;
    const int b  = bn >> 4, n = bn & 15;
    const int qb = 31 - (int)blockIdx.x;   // heavy blocks dispatched first
    const int q0 = qb * 64;
    const int qw = q0 + w * 16;

    const size_t sbase = ((size_t)(b * 16 + n)) * SEQ * HSIZE;
    const int    ebase = n * SEQ * HSIZE;

    // swizzle constants: frag-read key reduces to l16&7 for all tiles
    const int key8 = (l16 & 7) << 3;
    const int ec0  = ((quad * 8) ^ key8) * 2;        // byte offset in 128B row
    const int ec1  = ((32 + quad * 8) ^ key8) * 2;

    // Q fragments (plain layout)
    bf16x8 qf0 = *(const bf16x8*)(Qb + sbase + (size_t)(qw + l16) * 64 + quad * 8);
    bf16x8 qf1 = *(const bf16x8*)(Qb + sbase + (size_t)(qw + l16) * 64 + 32 + quad * 8);

    // pos-gather push-permute setup (per rg): dest lane + which-register cond
    int dsta[4];
    bool condp[4];
#pragma unroll
    for (int rg = 0; rg < 4; ++rg) {
        int rr   = quad * 4 + rg;
        int l16c = (rr + 15 - l16) & 15;   // consumer lane this lane pushes to
        dsta[rg]  = ((lane & 48) + l16c) << 2;
        condp[rg] = rr > l16c;             // consumer wants pa[4-j] vs pa[3-j]
    }

    // staging coords (8 rows per gload16 per wave-instr, 128B rows)
    const int r8 = t >> 3;          // 0..31
    const int c8 = (t & 7) * 8;     // element col within row

    f32x4 O[4] = {};
    float lsum[4] = {0.f, 0.f, 0.f, 0.f};

    for (int kt = 0; kt <= qb; ++kt) {
        const int k0 = kt * 64;
        const int Dr = q0 - k0 - 63;   // band start d for this tile
        __syncthreads();
        // K / Vt tiles (pre-swizzled in global -> linear DMA)
        gload16(Kb + sbase + (size_t)(k0 + r8) * 64 + c8, (char*)Ks + t * 16);
        gload16(Kb + sbase + (size_t)(k0 + 32 + r8) * 64 + c8, (char*)Ks + 4096 + t * 16);
        gload16(Vtb + sbase + (size_t)r8 * SEQ + k0 + c8, (char*)Vts + t * 16);
        gload16(Vtb + sbase + (size_t)(32 + r8) * SEQ + k0 + c8, (char*)Vts + 4096 + t * 16);
        // emb band ring: 64 new rows (d in [Dr, Dr+63]); full 128 on first iter.
        // Negative d reads land in vtbuf (valid memory), masked later.
        {
            char* dst = (char*)Es + ((Dr + 63) & 127) * 128;
            gload16(Eb + ebase + (Dr + r8) * 64 + c8, dst + t * 16);
            gload16(Eb + ebase + (Dr + 32 + r8) * 64 + c8, dst + 4096 + t * 16);
        }
        if (kt == 0) {
            char* dst = (char*)Es + ((Dr + 127) & 127) * 128;
            gload16(Eb + ebase + (Dr + 64 + r8) * 64 + c8, dst + t * 16);
            gload16(Eb + ebase + (Dr + 96 + r8) * 64 + c8, dst + 4096 + t * 16);
        }
        __syncthreads();

        // --- content scores ---
        f32x4 S[4];
#pragma unroll
        for (int j = 0; j < 4; ++j) {
            const char* kp = (const char*)Ks + (j * 16 + l16) * 128;
            bf16x8 kf0 = *(const bf16x8*)(kp + ec0);
            bf16x8 kf1 = *(const bf16x8*)(kp + ec1);
            f32x4 acc = {0,0,0,0};
            acc = __builtin_amdgcn_mfma_f32_16x16x32_bf16(qf1, kf1, acc, 0, 0, 0);
            acc = __builtin_amdgcn_mfma_f32_16x16x32_bf16(qf0, kf0, acc, 0, 0, 0);
            S[j] = acc;
        }

        // --- pos band: 5 subtiles, rows phys = (q0-64kt+16w+16jj+l16)&127 ---
        f32x4 pa[5];
        const int pbase = q0 - 64 * kt + 16 * w + l16;   // >= 0
#pragma unroll
        for (int jj = 0; jj < 5; ++jj) {
            const char* ep = (const char*)Es + ((pbase + 16 * jj) & 127) * 128;
            bf16x8 e0 = *(const bf16x8*)(ep + ec0);
            bf16x8 e1 = *(const bf16x8*)(ep + ec1);
            f32x4 acc = {0,0,0,0};
            acc = __builtin_amdgcn_mfma_f32_16x16x32_bf16(qf1, e1, acc, 0, 0, 0);
            acc = __builtin_amdgcn_mfma_f32_16x16x32_bf16(qf0, e0, acc, 0, 0, 0);
            pa[jj] = acc;
        }

        // --- diagonal gather via push-permute + mask + exp (no-max softmax) ---
#pragma unroll
        for (int j = 0; j < 4; ++j) {
#pragma unroll
            for (int rg = 0; rg < 4; ++rg) {
                float vsel = condp[rg] ? pa[4 - j][rg] : pa[3 - j][rg];
                int pv = __builtin_amdgcn_ds_permute(dsta[rg], __float_as_int(vsel));
                float sv = S[j][rg] + __int_as_float(pv);
                bool valid = (k0 + j * 16 + l16) <= (qw + quad * 4 + rg);
                S[j][rg] = valid ? __expf(sv) : 0.0f;
            }
        }
#pragma unroll
        for (int rg = 0; rg < 4; ++rg)
            lsum[rg] += S[0][rg] + S[1][rg] + S[2][rg] + S[3][rg];

        // --- P -> LDS (bf16, wave-private) -> A-frags ---
#pragma unroll
        for (int j = 0; j < 4; ++j)
#pragma unroll
            for (int rg = 0; rg < 4; ++rg)
                PS[w][quad * 4 + rg][j * 16 + l16] = (bf16)S[j][rg];
        bf16x8 pf0 = *(const bf16x8*)(&PS[w][l16][quad * 8]);
        bf16x8 pf1 = *(const bf16x8*)(&PS[w][l16][32 + quad * 8]);

        // --- PV ---
#pragma unroll
        for (int j4 = 0; j4 < 4; ++j4) {
            const char* vp = (const char*)Vts + (j4 * 16 + l16) * 128;
            bf16x8 v0 = *(const bf16x8*)(vp + ec0);
            bf16x8 v1 = *(const bf16x8*)(vp + ec1);
            O[j4] = __builtin_amdgcn_mfma_f32_16x16x32_bf16(pf1, v1, O[j4], 0, 0, 0);
            O[j4] = __builtin_amdgcn_mfma_f32_16x16x32_bf16(pf0, v0, O[j4], 0, 0, 0);
        }
    }

    // --- epilogue: reduce row-sums once, O /= l, write bf16 ---
#pragma unroll
    for (int rg = 0; rg < 4; ++rg) {
        float s = lsum[rg];
        s += __shfl_xor(s, 1);
        s += __shfl_xor(s, 2);
        s += __shfl_xor(s, 4);
        s += __shfl_xor(s, 8);
        float inv = 1.0f / s;
        int q = qw + quad * 4 + rg;
        size_t ro = ((size_t)(b * SEQ + q)) * NH + n * 64;
        o[ro +  0 + l16] = (bf16)(O[0][rg] * inv);
        o[ro + 16 + l16] = (bf16)(O[1][rg] * inv);
        o[ro + 32 + l16] = (bf16)(O[2][rg] * inv);
        o[ro + 48 + l16] = (bf16)(O[3][rg] * inv);
    }
}

// ---------------------------------------------------------------------------
extern "C" void kernel_launch(void* const* d_in, const int* in_sizes, int n_in,
                              void* d_out, int out_size, void* d_ws, size_t ws_size,
                              hipStream_t stream) {
    const float* inp        = (const float*)d_in[0];
    const float* qkv_w      = (const float*)d_in[1];
    const float* q_bias     = (const float*)d_in[2];
    const float* positional = (const float*)d_in[3];
    const float* out_kernel = (const float*)d_in[4];
    const float* out_bias   = (const float*)d_in[5];

    char* p = (char*)d_ws;
    auto alloc = [&](size_t bytes) {
        char* q = p; p += (bytes + 255) & ~(size_t)255; return q;
    };
    bf16* qbuf    = (bf16*)alloc((size_t)BATCH * HEADS * SEQ * HSIZE * 2);
    bf16* kbuf    = (bf16*)alloc((size_t)BATCH * HEADS * SEQ * HSIZE * 2);
    bf16* vtbuf   = (bf16*)alloc((size_t)BATCH * HEADS * SEQ * HSIZE * 2);
    bf16* embT    = (bf16*)alloc((size_t)HEADS * SEQ * HSIZE * 2);  // keep right after vtbuf (negative-d reads)
    bf16* sins_bf = (bf16*)alloc((size_t)SEQ * FREQS * 2);
    bf16* obuf    = (bf16*)alloc((size_t)BATCH * SEQ * NH * 2);
    bf16* a_bf    = (bf16*)alloc((size_t)BATCH * SEQ * DMODEL * 2);
    bf16* wt_qkv  = (bf16*)alloc((size_t)QKVN * DMODEL * 2);
    bf16* wt_out  = (bf16*)alloc((size_t)NH * DMODEL * 2);
    bf16* wt_pos  = (bf16*)alloc((size_t)NH * FREQS * 2);

    const float qkv_scale = (float)pow(3.0 * DMODEL * HSIZE * HEADS, -0.25);
    const float emb_scale = 0.0625f;   // 256^-0.5
    const float out_scale = 0.03125f;  // (1024*1024)^-0.25

    // prep: casts + transposes + sins
    cast_bf16<<<(BATCH * SEQ * DMODEL / 4 + 255) / 256, 256, 0, stream>>>(
        inp, a_bf, BATCH * SEQ * DMODEL / 4);
    transpose_cast<<<dim3(QKVN / 32, DMODEL / 32), 256, 0, stream>>>(
        qkv_w, wt_qkv, DMODEL, QKVN);
    transpose_cast<<<dim3(NH / 32, DMODEL / 32), 256, 0, stream>>>(
        out_kernel, wt_out, DMODEL, NH);
    transpose_cast<<<dim3(NH / 32, FREQS / 32), 256, 0, stream>>>(
        positional, wt_pos, FREQS, NH);
    sins_kernel<<<SEQ * FREQS / 256, 256, 0, stream>>>(sins_bf);

    // QK projection (cols 0..2047): Q plain, K swizzled
    mfma_gemm<1><<<dim3(16, 32), 256, 0, stream>>>(
        a_bf, wt_qkv, DMODEL, 0, qkv_scale, q_bias, nullptr, qbuf, kbuf);
    // V projection (cols 2048..3071), swapped operands -> swizzled Vt
    mfma_gemm<2><<<dim3(8, 32), 256, 0, stream>>>(
        a_bf, wt_qkv + (size_t)2048 * DMODEL, DMODEL, 2048, qkv_scale, nullptr,
        nullptr, vtbuf, nullptr);
    // emb -> swizzled embT[head][d][h]
    mfma_gemm<3><<<dim3(8, 16), 256, 0, stream>>>(
        sins_bf, wt_pos, FREQS, 0, emb_scale, nullptr, nullptr, embT, nullptr);

    // flash attention -> bf16 o
    attn_kernel<<<dim3(32, BATCH * HEADS), 256, 0, stream>>>(
        qbuf, kbuf, vtbuf, embT, obuf);

    // output projection (fp32 out)
    mfma_gemm<0><<<dim3(8, 32), 256, 0, stream>>>(
        obuf, wt_out, DMODEL, 0, out_scale, out_bias, (float*)d_out,
        nullptr, nullptr);
}

// Round 5
// 278.120 us; speedup vs baseline: 21.2253x; 1.1447x over previous
//
#include <hip/hip_runtime.h>
#include <math.h>

#define BATCH 2
#define SEQ 2048
#define DMODEL 1024
#define HEADS 16
#define HSIZE 64
#define FREQS 256
#define NH 1024
#define QKVN 3072

typedef __bf16 bf16;
typedef __bf16 bf16x8 __attribute__((ext_vector_type(8)));
typedef float f32x4 __attribute__((ext_vector_type(4)));

static __device__ __forceinline__ unsigned short bf16_bits(float v) {
    bf16 b = (bf16)v; return __builtin_bit_cast(unsigned short, b);
}

// async global->LDS, 16 bytes per lane; LDS dest = wave-uniform base + lane*16
static __device__ __forceinline__ void gload16(const void* g, void* l) {
    __builtin_amdgcn_global_load_lds(
        (const __attribute__((address_space(1))) unsigned int*)g,
        (__attribute__((address_space(3))) unsigned int*)l, 16, 0, 0);
}

// ---------------------------------------------------------------------------
// Sinusoid table (fp64 to match numpy) -> bf16 [SEQ][FREQS]
// ---------------------------------------------------------------------------
__global__ void sins_kernel(bf16* __restrict__ sins) {
    int i = blockIdx.x * blockDim.x + threadIdx.x;
    int s = i >> 8;
    int f = i & 255;
    double e = -(double)((f >> 1) << 1) / (double)FREQS;
    double invf = pow(10000.0, e);
    double ang = (double)s * invf;
    double v = (f & 1) ? cos(ang) : sin(ang);
    sins[i] = (bf16)(float)(1.4142135623730951 * v);
}

// ---------------------------------------------------------------------------
// fp32 -> bf16 elementwise cast (vectorized), n4 = elements/4
// ---------------------------------------------------------------------------
__global__ void cast_bf16(const float* __restrict__ src, bf16* __restrict__ dst, int n4) {
    int i = blockIdx.x * blockDim.x + threadIdx.x;
    if (i >= n4) return;
    float4 v = ((const float4*)src)[i];
    ushort4 o;
    o.x = bf16_bits(v.x); o.y = bf16_bits(v.y);
    o.z = bf16_bits(v.z); o.w = bf16_bits(v.w);
    ((ushort4*)dst)[i] = o;
}

// ---------------------------------------------------------------------------
// fp32 [R][C] -> bf16 [C][R] transpose+cast, 32x32 LDS tiles, block=256
// ---------------------------------------------------------------------------
__global__ __launch_bounds__(256) void transpose_cast(
    const float* __restrict__ src, bf16* __restrict__ dst, int R, int C)
{
    __shared__ float tile[32][33];
    const int tx = threadIdx.x & 31, ty = threadIdx.x >> 5;
    const int c0 = blockIdx.x * 32, r0 = blockIdx.y * 32;
#pragma unroll
    for (int i = 0; i < 4; i++)
        tile[ty + i * 8][tx] = src[(size_t)(r0 + ty + i * 8) * C + c0 + tx];
    __syncthreads();
#pragma unroll
    for (int i = 0; i < 4; i++)
        dst[(size_t)(c0 + ty + i * 8) * R + r0 + tx] = (bf16)tile[tx][ty + i * 8];
}

// ---------------------------------------------------------------------------
// bf16 MFMA GEMM: C[M][N] = A[M][K] @ Bt[N][K]^T, 128x128 tile, BK=32.
// EPI 0: out-proj fp32 = acc*alpha + bias[col]
// EPI 1: merged QKV: n0<1024 -> Q (plain, (acc*a+bias)*0.125);
//        1024..2047 -> K swizzled; >=2048 -> swapped-operand Vt swizzled
// EPI 3: embT[head][d][h^(((d+63)&7)<<3)]
// ---------------------------------------------------------------------------
template<int EPI>
__global__ __launch_bounds__(256) void mfma_gemm(
    const bf16* __restrict__ A, const bf16* __restrict__ Bt,
    int K, float alpha, const float* __restrict__ bias,
    float* __restrict__ outf, bf16* __restrict__ ob0, bf16* __restrict__ ob1,
    bf16* __restrict__ ob2)
{
    __shared__ __align__(16) bf16 Atile[128 * 32];
    __shared__ __align__(16) bf16 Btile[128 * 32];

    const int t    = threadIdx.x;
    const int lane = t & 63;
    const int w    = t >> 6;
    const int quad = lane >> 4;
    const int l16  = lane & 15;
    const int m0   = blockIdx.y * 128;
    const int n0   = blockIdx.x * 128;
    const int wm   = (w >> 1) * 64;
    const int wn   = (w & 1) * 64;
    const bool swapv = (EPI == 1) && (n0 >= 2048);

    const int rS  = t >> 2;
    const int cS  = (t & 3) ^ ((rS >> 1) & 3);
    const bf16* ag0 = A  + (size_t)(m0 + rS) * K + cS * 8;
    const bf16* ag1 = A  + (size_t)(m0 + rS + 64) * K + cS * 8;
    const bf16* bg0 = Bt + (size_t)(n0 + rS) * K + cS * 8;
    const bf16* bg1 = Bt + (size_t)(n0 + rS + 64) * K + cS * 8;
    bf16* al0 = Atile + t * 8;
    bf16* al1 = Atile + (t + 256) * 8;
    bf16* bl0 = Btile + t * 8;
    bf16* bl1 = Btile + (t + 256) * 8;

    int aoff[4], boff[4];
#pragma unroll
    for (int mi = 0; mi < 4; ++mi) {
        int r = wm + mi * 16 + l16;
        aoff[mi] = r * 32 + ((quad ^ ((r >> 1) & 3)) * 8);
    }
#pragma unroll
    for (int ni = 0; ni < 4; ++ni) {
        int r = wn + ni * 16 + l16;
        boff[ni] = r * 32 + ((quad ^ ((r >> 1) & 3)) * 8);
    }

    f32x4 acc[4][4] = {};

    for (int kk = 0; kk < K; kk += 32) {
        __syncthreads();
        gload16(ag0, al0); gload16(ag1, al1);
        gload16(bg0, bl0); gload16(bg1, bl1);
        ag0 += 32; ag1 += 32; bg0 += 32; bg1 += 32;
        __syncthreads();

        bf16x8 af[4], bfr[4];
#pragma unroll
        for (int mi = 0; mi < 4; ++mi) af[mi] = *(const bf16x8*)(Atile + aoff[mi]);
#pragma unroll
        for (int ni = 0; ni < 4; ++ni) bfr[ni] = *(const bf16x8*)(Btile + boff[ni]);

        if (!swapv) {
#pragma unroll
            for (int mi = 0; mi < 4; ++mi)
#pragma unroll
                for (int ni = 0; ni < 4; ++ni)
                    acc[mi][ni] = __builtin_amdgcn_mfma_f32_16x16x32_bf16(
                        af[mi], bfr[ni], acc[mi][ni], 0, 0, 0);
        } else {
#pragma unroll
            for (int mi = 0; mi < 4; ++mi)
#pragma unroll
                for (int ni = 0; ni < 4; ++ni)
                    acc[mi][ni] = __builtin_amdgcn_mfma_f32_16x16x32_bf16(
                        bfr[ni], af[mi], acc[mi][ni], 0, 0, 0);
        }
    }

    if constexpr (EPI == 0) {
#pragma unroll
        for (int mi = 0; mi < 4; ++mi)
#pragma unroll
            for (int ni = 0; ni < 4; ++ni) {
                int col = n0 + wn + ni * 16 + l16;
                float bb = bias[col];
#pragma unroll
                for (int rg = 0; rg < 4; ++rg) {
                    int row = m0 + wm + mi * 16 + quad * 4 + rg;
                    outf[(size_t)row * NH + col] = acc[mi][ni][rg] * alpha + bb;
                }
            }
    } else if constexpr (EPI == 1) {
        if (n0 >= 2048) {
            // swapped: acc[mi][ni] rows = head-cols, cols = seq-rows -> Vt
#pragma unroll
            for (int mi = 0; mi < 4; ++mi)
#pragma unroll
                for (int ni = 0; ni < 4; ++ni) {
                    int mcol = m0 + wm + mi * 16 + l16;
                    int bb = mcol >> 11, s = mcol & 2047;
#pragma unroll
                    for (int rg = 0; rg < 4; ++rg) {
                        int hg = n0 + wn + ni * 16 + quad * 4 + rg;
                        int head = (hg & 1023) >> 6, h = hg & 63;
                        int ss = s ^ ((h & 7) << 3);
                        ob2[((size_t)((bb * 16 + head) * 64 + h)) * SEQ + ss] =
                            (bf16)(acc[mi][ni][rg] * alpha);
                    }
                }
        } else {
            const int whichk = (n0 >= 1024);
#pragma unroll
            for (int mi = 0; mi < 4; ++mi)
#pragma unroll
                for (int ni = 0; ni < 4; ++ni) {
                    int cg   = (n0 + wn + ni * 16 + l16) & 1023;
                    int head = cg >> 6, h = cg & 63;
                    float qbv = whichk ? 0.0f : bias[cg];
#pragma unroll
                    for (int rg = 0; rg < 4; ++rg) {
                        int row = m0 + wm + mi * 16 + quad * 4 + rg;
                        int bb = row >> 11, s = row & 2047;
                        float v = acc[mi][ni][rg] * alpha;
                        if (whichk) {
                            int hs = h ^ ((s & 7) << 3);
                            ob1[((size_t)((bb * 16 + head) * SEQ + s)) * 64 + hs] = (bf16)v;
                        } else {
                            ob0[((size_t)((bb * 16 + head) * SEQ + s)) * 64 + h] =
                                (bf16)((v + qbv) * 0.125f);
                        }
                    }
                }
        }
    } else {  // EPI == 3: embT[head][d][h'] chunk-swizzled by (d+63)&7
#pragma unroll
        for (int mi = 0; mi < 4; ++mi)
#pragma unroll
            for (int ni = 0; ni < 4; ++ni) {
                int col = n0 + wn + ni * 16 + l16;
                int head = col >> 6, h = col & 63;
#pragma unroll
                for (int rg = 0; rg < 4; ++rg) {
                    int d = m0 + wm + mi * 16 + quad * 4 + rg;
                    int hs = h ^ (((d + 63) & 7) << 3);
                    ob0[((size_t)(head * SEQ + d)) * 64 + hs] =
                        (bf16)(acc[mi][ni][rg] * alpha);
                }
            }
    }
}

// ---------------------------------------------------------------------------
// MFMA flash attention v5: 128-row Q tile (2 chunks/wave), double-buffered
// K/V prefetch, 256-row Es ring, one barrier per k-tile, no-max softmax,
// ds_permute diagonal gather.
// Grid: (32 bn, 16 q-chunks); qc mapped so paired CU blocks sum to 34 tiles.
// ---------------------------------------------------------------------------
__global__ __launch_bounds__(256, 2) void attn_kernel(
    const bf16* __restrict__ Qb, const bf16* __restrict__ Kb,
    const bf16* __restrict__ Vtb, const bf16* __restrict__ Eb,
    bf16* __restrict__ o)
{
    __shared__ __align__(16) bf16 Ks[2][4096];
    __shared__ __align__(16) bf16 Vts[2][4096];
    __shared__ __align__(16) bf16 Es[256 * 64];      // ring: slot = (d-q0+63)&255
    __shared__ __align__(16) bf16 PS[4][16][72];

    const int t    = threadIdx.x;
    const int lane = t & 63;
    const int w    = t >> 6;
    const int quad = lane >> 4;
    const int l16  = lane & 15;

    const int bx = blockIdx.x;
    const int b  = bx >> 4, n = bx & 15;
    // pairing: y and y+8 give qc summing to 15 -> constant 34 tiles per CU pair
    const int yy = blockIdx.y;
    const int qc = (yy < 8) ? (15 - 2 * yy) : (2 * yy - 16);
    const int q0 = qc * 128;
    const int KT = 2 * qc + 2;
    const int qw0 = q0 + 16 * w;
    const int qw1 = qw0 + 64;

    const bf16* __restrict__ Qp = Qb  + (size_t)bx * SEQ * 64;
    const bf16* __restrict__ Kp = Kb  + (size_t)bx * SEQ * 64;
    const bf16* __restrict__ Vp = Vtb + (size_t)bx * SEQ * 64;
    const bf16* __restrict__ Ep = Eb  + (size_t)n  * SEQ * 64;

    const int key8 = (l16 & 7) << 3;
    const int ec0  = ((quad * 8) ^ key8) * 2;
    const int ec1  = ((32 + quad * 8) ^ key8) * 2;

    // Q fragments for both chunks
    bf16x8 qf[2][2];
    qf[0][0] = *(const bf16x8*)(Qp + (size_t)(qw0 + l16) * 64 + quad * 8);
    qf[0][1] = *(const bf16x8*)(Qp + (size_t)(qw0 + l16) * 64 + 32 + quad * 8);
    qf[1][0] = *(const bf16x8*)(Qp + (size_t)(qw1 + l16) * 64 + quad * 8);
    qf[1][1] = *(const bf16x8*)(Qp + (size_t)(qw1 + l16) * 64 + 32 + quad * 8);

    // pos push-permute setup
    int dsta[4];
    bool condp[4];
#pragma unroll
    for (int rg = 0; rg < 4; ++rg) {
        int rr   = quad * 4 + rg;
        int l16c = (rr + 15 - l16) & 15;
        dsta[rg]  = ((lane & 48) + l16c) << 2;
        condp[rg] = rr > l16c;
    }

    f32x4 O[2][4] = {};
    float lsum[2][4] = {};

    // preload tile 0 (K/V buf0) + full 192-row E window (ring slots 0..191)
    {
        gload16(Kp + t * 8,        (char*)Ks[0] + t * 16);
        gload16(Kp + 2048 + t * 8, (char*)Ks[0] + 4096 + t * 16);
        gload16(Vp + (size_t)(t >> 3) * SEQ + (t & 7) * 8,        (char*)Vts[0] + t * 16);
        gload16(Vp + (size_t)((t >> 3) + 32) * SEQ + (t & 7) * 8, (char*)Vts[0] + 4096 + t * 16);
        const long D0 = (long)q0 - 63;
#pragma unroll
        for (int g = 0; g < 6; ++g)
            gload16(Ep + (D0 + 32 * g) * 64 + t * 8, (char*)Es + g * 4096 + t * 16);
    }

    for (int kt = 0; kt < KT; ++kt) {
        const int k0 = kt * 64;
        __syncthreads();   // drains prefetch for kt; all waves past kt-1 reads

        // prefetch tile kt+1 into alt buffers + next 64 ring rows
        const int nt = kt + 1;
        if (nt < KT) {
            bf16* kd = Ks[nt & 1];
            bf16* vd = Vts[nt & 1];
            const bf16* ksrc = Kp + nt * 4096;
            gload16(ksrc + t * 8,        (char*)kd + t * 16);
            gload16(ksrc + 2048 + t * 8, (char*)kd + 4096 + t * 16);
            gload16(Vp + (size_t)(t >> 3) * SEQ + nt * 64 + (t & 7) * 8,
                    (char*)vd + t * 16);
            gload16(Vp + (size_t)((t >> 3) + 32) * SEQ + nt * 64 + (t & 7) * 8,
                    (char*)vd + 4096 + t * 16);
            const long d0 = (long)q0 - nt * 64 - 63;
            const int rI = (-64 * nt) & 255;   // 64-aligned, disjoint from window
            gload16(Ep + d0 * 64 + t * 8,        (char*)Es + rI * 128 + t * 16);
            gload16(Ep + (d0 + 32) * 64 + t * 8, (char*)Es + rI * 128 + 4096 + t * 16);
        }

        // K / V fragments (register-cached, shared by both chunks)
        const char* kb = (const char*)Ks[kt & 1];
        const char* vb = (const char*)Vts[kt & 1];
        bf16x8 kf[4][2], vf[4][2];
#pragma unroll
        for (int j = 0; j < 4; ++j) {
            const char* kp = kb + (j * 16 + l16) * 128;
            kf[j][0] = *(const bf16x8*)(kp + ec0);
            kf[j][1] = *(const bf16x8*)(kp + ec1);
            const char* vp = vb + (j * 16 + l16) * 128;
            vf[j][0] = *(const bf16x8*)(vp + ec0);
            vf[j][1] = *(const bf16x8*)(vp + ec1);
        }

        const bool last = (nt == KT);   // chunk0 fully masked on last tile
#pragma unroll
        for (int c = 0; c < 2; ++c) {
            if (c == 0 && last) continue;
            const int qwc = c ? qw1 : qw0;

            // pos band: 5 subtiles from ring
            f32x4 pa[5];
            const int rb = 16 * w + 64 * c - k0;
#pragma unroll
            for (int jj = 0; jj < 5; ++jj) {
                const char* ep = (const char*)Es + ((rb + 16 * jj + l16) & 255) * 128;
                bf16x8 e0 = *(const bf16x8*)(ep + ec0);
                bf16x8 e1 = *(const bf16x8*)(ep + ec1);
                f32x4 a = {0, 0, 0, 0};
                a = __builtin_amdgcn_mfma_f32_16x16x32_bf16(qf[c][1], e1, a, 0, 0, 0);
                a = __builtin_amdgcn_mfma_f32_16x16x32_bf16(qf[c][0], e0, a, 0, 0, 0);
                pa[jj] = a;
            }

            // content scores
            f32x4 S[4];
#pragma unroll
            for (int j = 0; j < 4; ++j) {
                f32x4 a = {0, 0, 0, 0};
                a = __builtin_amdgcn_mfma_f32_16x16x32_bf16(qf[c][1], kf[j][1], a, 0, 0, 0);
                a = __builtin_amdgcn_mfma_f32_16x16x32_bf16(qf[c][0], kf[j][0], a, 0, 0, 0);
                S[j] = a;
            }

            // diagonal gather + mask + exp (no-max softmax)
#pragma unroll
            for (int j = 0; j < 4; ++j) {
#pragma unroll
                for (int rg = 0; rg < 4; ++rg) {
                    float vsel = condp[rg] ? pa[4 - j][rg] : pa[3 - j][rg];
                    int pv = __builtin_amdgcn_ds_permute(dsta[rg], __float_as_int(vsel));
                    float sv = S[j][rg] + __int_as_float(pv);
                    bool valid = (k0 + j * 16 + l16) <= (qwc + quad * 4 + rg);
                    S[j][rg] = valid ? __expf(sv) : 0.0f;
                }
            }
#pragma unroll
            for (int rg = 0; rg < 4; ++rg)
                lsum[c][rg] += S[0][rg] + S[1][rg] + S[2][rg] + S[3][rg];

            // P -> LDS (wave-private) -> A-frags
#pragma unroll
            for (int j = 0; j < 4; ++j)
#pragma unroll
                for (int rg = 0; rg < 4; ++rg)
                    PS[w][quad * 4 + rg][j * 16 + l16] = (bf16)S[j][rg];
            bf16x8 pf0 = *(const bf16x8*)(&PS[w][l16][quad * 8]);
            bf16x8 pf1 = *(const bf16x8*)(&PS[w][l16][32 + quad * 8]);

            // PV
#pragma unroll
            for (int j4 = 0; j4 < 4; ++j4) {
                O[c][j4] = __builtin_amdgcn_mfma_f32_16x16x32_bf16(pf1, vf[j4][1], O[c][j4], 0, 0, 0);
                O[c][j4] = __builtin_amdgcn_mfma_f32_16x16x32_bf16(pf0, vf[j4][0], O[c][j4], 0, 0, 0);
            }
        }
    }

    // epilogue: reduce row-sums, normalize, write bf16
#pragma unroll
    for (int c = 0; c < 2; ++c) {
#pragma unroll
        for (int rg = 0; rg < 4; ++rg) {
            float s = lsum[c][rg];
            s += __shfl_xor(s, 1);
            s += __shfl_xor(s, 2);
            s += __shfl_xor(s, 4);
            s += __shfl_xor(s, 8);
            float inv = 1.0f / s;
            int q = (c ? qw1 : qw0) + quad * 4 + rg;
            size_t ro = ((size_t)(b * SEQ + q)) * NH + n * 64;
            o[ro +  0 + l16] = (bf16)(O[c][0][rg] * inv);
            o[ro + 16 + l16] = (bf16)(O[c][1][rg] * inv);
            o[ro + 32 + l16] = (bf16)(O[c][2][rg] * inv);
            o[ro + 48 + l16] = (bf16)(O[c][3][rg] * inv);
        }
    }
}

// ---------------------------------------------------------------------------
extern "C" void kernel_launch(void* const* d_in, const int* in_sizes, int n_in,
                              void* d_out, int out_size, void* d_ws, size_t ws_size,
                              hipStream_t stream) {
    const float* inp        = (const float*)d_in[0];
    const float* qkv_w      = (const float*)d_in[1];
    const float* q_bias     = (const float*)d_in[2];
    const float* positional = (const float*)d_in[3];
    const float* out_kernel = (const float*)d_in[4];
    const float* out_bias   = (const float*)d_in[5];

    char* p = (char*)d_ws;
    auto alloc = [&](size_t bytes) {
        char* q = p; p += (bytes + 255) & ~(size_t)255; return q;
    };
    bf16* qbuf    = (bf16*)alloc((size_t)BATCH * HEADS * SEQ * HSIZE * 2);
    bf16* kbuf    = (bf16*)alloc((size_t)BATCH * HEADS * SEQ * HSIZE * 2);
    bf16* vtbuf   = (bf16*)alloc((size_t)BATCH * HEADS * SEQ * HSIZE * 2);
    bf16* embT    = (bf16*)alloc((size_t)HEADS * SEQ * HSIZE * 2);  // after vtbuf (negative-d slack)
    bf16* sins_bf = (bf16*)alloc((size_t)SEQ * FREQS * 2);          // after embT (d>=2048 slack)
    bf16* obuf    = (bf16*)alloc((size_t)BATCH * SEQ * NH * 2);
    bf16* a_bf    = (bf16*)alloc((size_t)BATCH * SEQ * DMODEL * 2);
    bf16* wt_qkv  = (bf16*)alloc((size_t)QKVN * DMODEL * 2);
    bf16* wt_out  = (bf16*)alloc((size_t)NH * DMODEL * 2);
    bf16* wt_pos  = (bf16*)alloc((size_t)NH * FREQS * 2);

    const float qkv_scale = (float)pow(3.0 * DMODEL * HSIZE * HEADS, -0.25);
    const float emb_scale = 0.0625f;   // 256^-0.5
    const float out_scale = 0.03125f;  // (1024*1024)^-0.25

    // prep
    cast_bf16<<<(BATCH * SEQ * DMODEL / 4 + 255) / 256, 256, 0, stream>>>(
        inp, a_bf, BATCH * SEQ * DMODEL / 4);
    transpose_cast<<<dim3(QKVN / 32, DMODEL / 32), 256, 0, stream>>>(
        qkv_w, wt_qkv, DMODEL, QKVN);
    transpose_cast<<<dim3(NH / 32, DMODEL / 32), 256, 0, stream>>>(
        out_kernel, wt_out, DMODEL, NH);
    transpose_cast<<<dim3(NH / 32, FREQS / 32), 256, 0, stream>>>(
        positional, wt_pos, FREQS, NH);
    sins_kernel<<<SEQ * FREQS / 256, 256, 0, stream>>>(sins_bf);

    // merged QKV projection: Q plain, K swizzled, V swapped->Vt swizzled
    mfma_gemm<1><<<dim3(24, 32), 256, 0, stream>>>(
        a_bf, wt_qkv, DMODEL, qkv_scale, q_bias, nullptr, qbuf, kbuf, vtbuf);
    // emb -> swizzled embT[head][d][h]
    mfma_gemm<3><<<dim3(8, 16), 256, 0, stream>>>(
        sins_bf, wt_pos, FREQS, emb_scale, nullptr, nullptr, embT, nullptr, nullptr);

    // flash attention -> bf16 o
    attn_kernel<<<dim3(32, 16), 256, 0, stream>>>(
        qbuf, kbuf, vtbuf, embT, obuf);

    // output projection (fp32 out)
    mfma_gemm<0><<<dim3(8, 32), 256, 0, stream>>>(
        obuf, wt_out, DMODEL, out_scale, out_bias, (float*)d_out,
        nullptr, nullptr, nullptr);
}

// Round 6
// 263.576 us; speedup vs baseline: 22.3964x; 1.0552x over previous
//
#include <hip/hip_runtime.h>
#include <math.h>

#define BATCH 2
#define SEQ 2048
#define DMODEL 1024
#define HEADS 16
#define HSIZE 64
#define FREQS 256
#define NH 1024
#define QKVN 3072

typedef __bf16 bf16;
typedef __bf16 bf16x8 __attribute__((ext_vector_type(8)));
typedef float f32x4 __attribute__((ext_vector_type(4)));

static __device__ __forceinline__ unsigned short bf16_bits(float v) {
    bf16 b = (bf16)v; return __builtin_bit_cast(unsigned short, b);
}

// async global->LDS, 16 bytes per lane; LDS dest = wave-uniform base + lane*16
static __device__ __forceinline__ void gload16(const void* g, void* l) {
    __builtin_amdgcn_global_load_lds(
        (const __attribute__((address_space(1))) unsigned int*)g,
        (__attribute__((address_space(3))) unsigned int*)l, 16, 0, 0);
}

// ---------------------------------------------------------------------------
// Merged prep: fp32->bf16 cast of input, fp64 sinusoid table, and the three
// weight transpose+casts, decoded from a 1D block range. One launch.
//   [0,4096)        cast input (4096*256*4 floats)
//   [4096,6144)     sins table
//   [6144,9216)     transpose qkv_w   (1024x3072 -> 3072x1024)
//   [9216,10240)    transpose out_kernel (1024x1024)
//   [10240,10496)   transpose positional (256x1024 -> 1024x256)
// ---------------------------------------------------------------------------
__global__ __launch_bounds__(256) void prep_kernel(
    const float* __restrict__ inp, const float* __restrict__ qkv_w,
    const float* __restrict__ out_kernel, const float* __restrict__ positional,
    bf16* __restrict__ a_bf, bf16* __restrict__ wt_qkv,
    bf16* __restrict__ wt_out, bf16* __restrict__ wt_pos,
    bf16* __restrict__ sins_bf)
{
    __shared__ float tile[32][33];
    const int id = blockIdx.x, t = threadIdx.x;

    if (id < 4096) {            // input cast
        int i = id * 256 + t;
        float4 v = ((const float4*)inp)[i];
        ushort4 o;
        o.x = bf16_bits(v.x); o.y = bf16_bits(v.y);
        o.z = bf16_bits(v.z); o.w = bf16_bits(v.w);
        ((ushort4*)a_bf)[i] = o;
        return;
    }
    if (id < 6144) {            // sinusoid table (fp64, matches numpy)
        int i = (id - 4096) * 256 + t;
        int s = i >> 8, f = i & 255;
        double e = -(double)((f >> 1) << 1) / (double)FREQS;
        double invf = pow(10000.0, e);
        double ang = (double)s * invf;
        double v = (f & 1) ? cos(ang) : sin(ang);
        sins_bf[i] = (bf16)(float)(1.4142135623730951 * v);
        return;
    }
    int id2 = id - 6144;
    const float* src; bf16* dst; int R, C, c0, r0;
    if (id2 < 3072) {
        src = qkv_w; dst = wt_qkv; R = 1024; C = 3072;
        c0 = (id2 % 96) * 32; r0 = (id2 / 96) * 32;
    } else if (id2 < 4096) {
        id2 -= 3072;
        src = out_kernel; dst = wt_out; R = 1024; C = 1024;
        c0 = (id2 & 31) * 32; r0 = (id2 >> 5) * 32;
    } else {
        id2 -= 4096;
        src = positional; dst = wt_pos; R = 256; C = 1024;
        c0 = (id2 & 31) * 32; r0 = (id2 >> 5) * 32;
    }
    const int tx = t & 31, ty = t >> 5;
#pragma unroll
    for (int i = 0; i < 4; i++)
        tile[ty + i * 8][tx] = src[(size_t)(r0 + ty + i * 8) * C + c0 + tx];
    __syncthreads();
#pragma unroll
    for (int i = 0; i < 4; i++)
        dst[(size_t)(c0 + ty + i * 8) * R + r0 + tx] = (bf16)tile[tx][ty + i * 8];
}

// ---------------------------------------------------------------------------
// Pipelined bf16 MFMA GEMM: C[M][N] = A[M][K] @ Bt[N][K]^T, 128x128 tile,
// BK=32, double-buffered LDS, one barrier per K-iter (prefetch overlaps MFMA).
// EPI 0: out-proj fp32 = acc*alpha + bias[col]
// EPI 1: merged QKV+emb dispatch:
//   blockIdx.x < 24 -> QKV: n0<1024 Q plain; <2048 K swizzled; else
//                      swapped-operand Vt swizzled
//   blockIdx.x >= 24 -> emb tiles (A2/Bt2/alpha2): embT[head][d][h'] swizzled
// ---------------------------------------------------------------------------
template<int EPI>
__global__ __launch_bounds__(256) void mfma_gemm(
    const bf16* __restrict__ A, const bf16* __restrict__ Bt,
    int K, float alpha, const float* __restrict__ bias,
    float* __restrict__ outf, bf16* __restrict__ ob0, bf16* __restrict__ ob1,
    bf16* __restrict__ ob2,
    const bf16* __restrict__ A2, const bf16* __restrict__ Bt2,
    bf16* __restrict__ ob3, float alpha2)
{
    __shared__ __align__(16) bf16 Atile[2][128 * 32];
    __shared__ __align__(16) bf16 Btile[2][128 * 32];

    const int t    = threadIdx.x;
    const int lane = t & 63;
    const int w    = t >> 6;
    const int quad = lane >> 4;
    const int l16  = lane & 15;
    const int wm   = (w >> 1) * 64;
    const int wn   = (w & 1) * 64;

    bool embp = false;
    int m0 = blockIdx.y * 128, n0 = blockIdx.x * 128, Kl = K;
    const bf16* Ap = A; const bf16* Btp = Bt; float al = alpha;
    if constexpr (EPI == 1) {
        if (blockIdx.x >= 24) {
            if (blockIdx.y >= 16) return;   // emb has only 2048 rows
            embp = true;
            n0 = (blockIdx.x - 24) * 128;
            Kl = FREQS; Ap = A2; Btp = Bt2; al = alpha2;
        }
    }
    const bool swapv = (EPI == 1) && !embp && (n0 >= 2048);

    // staging coords (16B chunk swizzle)
    const int rS = t >> 2;
    const int cS = (t & 3) ^ ((rS >> 1) & 3);
    const bf16* ag0 = Ap  + (size_t)(m0 + rS) * Kl + cS * 8;
    const bf16* ag1 = ag0 + (size_t)64 * Kl;
    const bf16* bg0 = Btp + (size_t)(n0 + rS) * Kl + cS * 8;
    const bf16* bg1 = bg0 + (size_t)64 * Kl;

    // fragment LDS offsets (within one buffer)
    int aoff[4], boff[4];
#pragma unroll
    for (int mi = 0; mi < 4; ++mi) {
        int r = wm + mi * 16 + l16;
        aoff[mi] = r * 32 + ((quad ^ ((r >> 1) & 3)) * 8);
    }
#pragma unroll
    for (int ni = 0; ni < 4; ++ni) {
        int r = wn + ni * 16 + l16;
        boff[ni] = r * 32 + ((quad ^ ((r >> 1) & 3)) * 8);
    }

    // preload chunk 0 into buffer 0
    gload16(ag0, (char*)Atile[0] + t * 16);
    gload16(ag1, (char*)Atile[0] + 4096 + t * 16);
    gload16(bg0, (char*)Btile[0] + t * 16);
    gload16(bg1, (char*)Btile[0] + 4096 + t * 16);

    const int nK = Kl >> 5;
    f32x4 acc[4][4] = {};

    for (int kk = 0; kk < nK; ++kk) {
        __syncthreads();     // drains prefetch for kk (vmcnt) + prev reads
        if (kk + 1 < nK) {   // prefetch kk+1 into alternate buffer
            ag0 += 32; ag1 += 32; bg0 += 32; bg1 += 32;
            char* ad = (char*)Atile[(kk + 1) & 1];
            char* bd = (char*)Btile[(kk + 1) & 1];
            gload16(ag0, ad + t * 16); gload16(ag1, ad + 4096 + t * 16);
            gload16(bg0, bd + t * 16); gload16(bg1, bd + 4096 + t * 16);
        }
        const bf16* ab = Atile[kk & 1];
        const bf16* bb = Btile[kk & 1];
        bf16x8 af[4], bfr[4];
#pragma unroll
        for (int mi = 0; mi < 4; ++mi) af[mi] = *(const bf16x8*)(ab + aoff[mi]);
#pragma unroll
        for (int ni = 0; ni < 4; ++ni) bfr[ni] = *(const bf16x8*)(bb + boff[ni]);

        if (!swapv) {
#pragma unroll
            for (int mi = 0; mi < 4; ++mi)
#pragma unroll
                for (int ni = 0; ni < 4; ++ni)
                    acc[mi][ni] = __builtin_amdgcn_mfma_f32_16x16x32_bf16(
                        af[mi], bfr[ni], acc[mi][ni], 0, 0, 0);
        } else {
#pragma unroll
            for (int mi = 0; mi < 4; ++mi)
#pragma unroll
                for (int ni = 0; ni < 4; ++ni)
                    acc[mi][ni] = __builtin_amdgcn_mfma_f32_16x16x32_bf16(
                        bfr[ni], af[mi], acc[mi][ni], 0, 0, 0);
        }
    }

    if constexpr (EPI == 0) {
#pragma unroll
        for (int mi = 0; mi < 4; ++mi)
#pragma unroll
            for (int ni = 0; ni < 4; ++ni) {
                int col = n0 + wn + ni * 16 + l16;
                float bb = bias[col];
#pragma unroll
                for (int rg = 0; rg < 4; ++rg) {
                    int row = m0 + wm + mi * 16 + quad * 4 + rg;
                    outf[(size_t)row * NH + col] = acc[mi][ni][rg] * al + bb;
                }
            }
    } else {
        if (embp) {  // embT[head][d][h'] chunk-swizzled by (d+63)&7
#pragma unroll
            for (int mi = 0; mi < 4; ++mi)
#pragma unroll
                for (int ni = 0; ni < 4; ++ni) {
                    int col = n0 + wn + ni * 16 + l16;
                    int head = col >> 6, h = col & 63;
#pragma unroll
                    for (int rg = 0; rg < 4; ++rg) {
                        int d = m0 + wm + mi * 16 + quad * 4 + rg;
                        int hs = h ^ (((d + 63) & 7) << 3);
                        ob3[((size_t)(head * SEQ + d)) * 64 + hs] =
                            (bf16)(acc[mi][ni][rg] * al);
                    }
                }
        } else if (n0 >= 2048) {
            // swapped: acc rows = head-cols, cols = seq-rows -> Vt swizzled
#pragma unroll
            for (int mi = 0; mi < 4; ++mi)
#pragma unroll
                for (int ni = 0; ni < 4; ++ni) {
                    int mcol = m0 + wm + mi * 16 + l16;
                    int bb = mcol >> 11, s = mcol & 2047;
#pragma unroll
                    for (int rg = 0; rg < 4; ++rg) {
                        int hg = n0 + wn + ni * 16 + quad * 4 + rg;
                        int head = (hg & 1023) >> 6, h = hg & 63;
                        int ss = s ^ ((h & 7) << 3);
                        ob2[((size_t)((bb * 16 + head) * 64 + h)) * SEQ + ss] =
                            (bf16)(acc[mi][ni][rg] * al);
                    }
                }
        } else {
            const int whichk = (n0 >= 1024);
#pragma unroll
            for (int mi = 0; mi < 4; ++mi)
#pragma unroll
                for (int ni = 0; ni < 4; ++ni) {
                    int cg   = (n0 + wn + ni * 16 + l16) & 1023;
                    int head = cg >> 6, h = cg & 63;
                    float qbv = whichk ? 0.0f : bias[cg];
#pragma unroll
                    for (int rg = 0; rg < 4; ++rg) {
                        int row = m0 + wm + mi * 16 + quad * 4 + rg;
                        int bb = row >> 11, s = row & 2047;
                        float v = acc[mi][ni][rg] * al;
                        if (whichk) {
                            int hs = h ^ ((s & 7) << 3);
                            ob1[((size_t)((bb * 16 + head) * SEQ + s)) * 64 + hs] = (bf16)v;
                        } else {
                            ob0[((size_t)((bb * 16 + head) * SEQ + s)) * 64 + h] =
                                (bf16)((v + qbv) * 0.125f);
                        }
                    }
                }
        }
    }
}

// ---------------------------------------------------------------------------
// MFMA flash attention v5 (unchanged from round 5): 128-row Q tile,
// double-buffered K/V prefetch, 256-row Es ring, one barrier per k-tile,
// no-max softmax, ds_permute diagonal gather.
// ---------------------------------------------------------------------------
__global__ __launch_bounds__(256, 2) void attn_kernel(
    const bf16* __restrict__ Qb, const bf16* __restrict__ Kb,
    const bf16* __restrict__ Vtb, const bf16* __restrict__ Eb,
    bf16* __restrict__ o)
{
    __shared__ __align__(16) bf16 Ks[2][4096];
    __shared__ __align__(16) bf16 Vts[2][4096];
    __shared__ __align__(16) bf16 Es[256 * 64];
    __shared__ __align__(16) bf16 PS[4][16][72];

    const int t    = threadIdx.x;
    const int lane = t & 63;
    const int w    = t >> 6;
    const int quad = lane >> 4;
    const int l16  = lane & 15;

    const int bx = blockIdx.x;
    const int b  = bx >> 4, n = bx & 15;
    const int yy = blockIdx.y;
    const int qc = (yy < 8) ? (15 - 2 * yy) : (2 * yy - 16);
    const int q0 = qc * 128;
    const int KT = 2 * qc + 2;
    const int qw0 = q0 + 16 * w;
    const int qw1 = qw0 + 64;

    const bf16* __restrict__ Qp = Qb  + (size_t)bx * SEQ * 64;
    const bf16* __restrict__ Kp = Kb  + (size_t)bx * SEQ * 64;
    const bf16* __restrict__ Vp = Vtb + (size_t)bx * SEQ * 64;
    const bf16* __restrict__ Ep = Eb  + (size_t)n  * SEQ * 64;

    const int key8 = (l16 & 7) << 3;
    const int ec0  = ((quad * 8) ^ key8) * 2;
    const int ec1  = ((32 + quad * 8) ^ key8) * 2;

    bf16x8 qf[2][2];
    qf[0][0] = *(const bf16x8*)(Qp + (size_t)(qw0 + l16) * 64 + quad * 8);
    qf[0][1] = *(const bf16x8*)(Qp + (size_t)(qw0 + l16) * 64 + 32 + quad * 8);
    qf[1][0] = *(const bf16x8*)(Qp + (size_t)(qw1 + l16) * 64 + quad * 8);
    qf[1][1] = *(const bf16x8*)(Qp + (size_t)(qw1 + l16) * 64 + 32 + quad * 8);

    int dsta[4];
    bool condp[4];
#pragma unroll
    for (int rg = 0; rg < 4; ++rg) {
        int rr   = quad * 4 + rg;
        int l16c = (rr + 15 - l16) & 15;
        dsta[rg]  = ((lane & 48) + l16c) << 2;
        condp[rg] = rr > l16c;
    }

    f32x4 O[2][4] = {};
    float lsum[2][4] = {};

    {
        gload16(Kp + t * 8,        (char*)Ks[0] + t * 16);
        gload16(Kp + 2048 + t * 8, (char*)Ks[0] + 4096 + t * 16);
        gload16(Vp + (size_t)(t >> 3) * SEQ + (t & 7) * 8,        (char*)Vts[0] + t * 16);
        gload16(Vp + (size_t)((t >> 3) + 32) * SEQ + (t & 7) * 8, (char*)Vts[0] + 4096 + t * 16);
        const long D0 = (long)q0 - 63;
#pragma unroll
        for (int g = 0; g < 6; ++g)
            gload16(Ep + (D0 + 32 * g) * 64 + t * 8, (char*)Es + g * 4096 + t * 16);
    }

    for (int kt = 0; kt < KT; ++kt) {
        const int k0 = kt * 64;
        __syncthreads();

        const int nt = kt + 1;
        if (nt < KT) {
            bf16* kd = Ks[nt & 1];
            bf16* vd = Vts[nt & 1];
            const bf16* ksrc = Kp + nt * 4096;
            gload16(ksrc + t * 8,        (char*)kd + t * 16);
            gload16(ksrc + 2048 + t * 8, (char*)kd + 4096 + t * 16);
            gload16(Vp + (size_t)(t >> 3) * SEQ + nt * 64 + (t & 7) * 8,
                    (char*)vd + t * 16);
            gload16(Vp + (size_t)((t >> 3) + 32) * SEQ + nt * 64 + (t & 7) * 8,
                    (char*)vd + 4096 + t * 16);
            const long d0 = (long)q0 - nt * 64 - 63;
            const int rI = (-64 * nt) & 255;
            gload16(Ep + d0 * 64 + t * 8,        (char*)Es + rI * 128 + t * 16);
            gload16(Ep + (d0 + 32) * 64 + t * 8, (char*)Es + rI * 128 + 4096 + t * 16);
        }

        const char* kb = (const char*)Ks[kt & 1];
        const char* vb = (const char*)Vts[kt & 1];
        bf16x8 kf[4][2], vf[4][2];
#pragma unroll
        for (int j = 0; j < 4; ++j) {
            const char* kp = kb + (j * 16 + l16) * 128;
            kf[j][0] = *(const bf16x8*)(kp + ec0);
            kf[j][1] = *(const bf16x8*)(kp + ec1);
            const char* vp = vb + (j * 16 + l16) * 128;
            vf[j][0] = *(const bf16x8*)(vp + ec0);
            vf[j][1] = *(const bf16x8*)(vp + ec1);
        }

        const bool last = (nt == KT);
#pragma unroll
        for (int c = 0; c < 2; ++c) {
            if (c == 0 && last) continue;
            const int qwc = c ? qw1 : qw0;

            f32x4 pa[5];
            const int rb = 16 * w + 64 * c - k0;
#pragma unroll
            for (int jj = 0; jj < 5; ++jj) {
                const char* ep = (const char*)Es + ((rb + 16 * jj + l16) & 255) * 128;
                bf16x8 e0 = *(const bf16x8*)(ep + ec0);
                bf16x8 e1 = *(const bf16x8*)(ep + ec1);
                f32x4 a = {0, 0, 0, 0};
                a = __builtin_amdgcn_mfma_f32_16x16x32_bf16(qf[c][1], e1, a, 0, 0, 0);
                a = __builtin_amdgcn_mfma_f32_16x16x32_bf16(qf[c][0], e0, a, 0, 0, 0);
                pa[jj] = a;
            }

            f32x4 S[4];
#pragma unroll
            for (int j = 0; j < 4; ++j) {
                f32x4 a = {0, 0, 0, 0};
                a = __builtin_amdgcn_mfma_f32_16x16x32_bf16(qf[c][1], kf[j][1], a, 0, 0, 0);
                a = __builtin_amdgcn_mfma_f32_16x16x32_bf16(qf[c][0], kf[j][0], a, 0, 0, 0);
                S[j] = a;
            }

#pragma unroll
            for (int j = 0; j < 4; ++j) {
#pragma unroll
                for (int rg = 0; rg < 4; ++rg) {
                    float vsel = condp[rg] ? pa[4 - j][rg] : pa[3 - j][rg];
                    int pv = __builtin_amdgcn_ds_permute(dsta[rg], __float_as_int(vsel));
                    float sv = S[j][rg] + __int_as_float(pv);
                    bool valid = (k0 + j * 16 + l16) <= (qwc + quad * 4 + rg);
                    S[j][rg] = valid ? __expf(sv) : 0.0f;
                }
            }
#pragma unroll
            for (int rg = 0; rg < 4; ++rg)
                lsum[c][rg] += S[0][rg] + S[1][rg] + S[2][rg] + S[3][rg];

#pragma unroll
            for (int j = 0; j < 4; ++j)
#pragma unroll
                for (int rg = 0; rg < 4; ++rg)
                    PS[w][quad * 4 + rg][j * 16 + l16] = (bf16)S[j][rg];
            bf16x8 pf0 = *(const bf16x8*)(&PS[w][l16][quad * 8]);
            bf16x8 pf1 = *(const bf16x8*)(&PS[w][l16][32 + quad * 8]);

#pragma unroll
            for (int j4 = 0; j4 < 4; ++j4) {
                O[c][j4] = __builtin_amdgcn_mfma_f32_16x16x32_bf16(pf1, vf[j4][1], O[c][j4], 0, 0, 0);
                O[c][j4] = __builtin_amdgcn_mfma_f32_16x16x32_bf16(pf0, vf[j4][0], O[c][j4], 0, 0, 0);
            }
        }
    }

#pragma unroll
    for (int c = 0; c < 2; ++c) {
#pragma unroll
        for (int rg = 0; rg < 4; ++rg) {
            float s = lsum[c][rg];
            s += __shfl_xor(s, 1);
            s += __shfl_xor(s, 2);
            s += __shfl_xor(s, 4);
            s += __shfl_xor(s, 8);
            float inv = 1.0f / s;
            int q = (c ? qw1 : qw0) + quad * 4 + rg;
            size_t ro = ((size_t)(b * SEQ + q)) * NH + n * 64;
            o[ro +  0 + l16] = (bf16)(O[c][0][rg] * inv);
            o[ro + 16 + l16] = (bf16)(O[c][1][rg] * inv);
            o[ro + 32 + l16] = (bf16)(O[c][2][rg] * inv);
            o[ro + 48 + l16] = (bf16)(O[c][3][rg] * inv);
        }
    }
}

// ---------------------------------------------------------------------------
extern "C" void kernel_launch(void* const* d_in, const int* in_sizes, int n_in,
                              void* d_out, int out_size, void* d_ws, size_t ws_size,
                              hipStream_t stream) {
    const float* inp        = (const float*)d_in[0];
    const float* qkv_w      = (const float*)d_in[1];
    const float* q_bias     = (const float*)d_in[2];
    const float* positional = (const float*)d_in[3];
    const float* out_kernel = (const float*)d_in[4];
    const float* out_bias   = (const float*)d_in[5];

    char* p = (char*)d_ws;
    auto alloc = [&](size_t bytes) {
        char* q = p; p += (bytes + 255) & ~(size_t)255; return q;
    };
    bf16* qbuf    = (bf16*)alloc((size_t)BATCH * HEADS * SEQ * HSIZE * 2);
    bf16* kbuf    = (bf16*)alloc((size_t)BATCH * HEADS * SEQ * HSIZE * 2);
    bf16* vtbuf   = (bf16*)alloc((size_t)BATCH * HEADS * SEQ * HSIZE * 2);
    bf16* embT    = (bf16*)alloc((size_t)HEADS * SEQ * HSIZE * 2);  // after vtbuf (negative-d slack)
    bf16* sins_bf = (bf16*)alloc((size_t)SEQ * FREQS * 2);          // after embT (d>=2048 slack)
    bf16* obuf    = (bf16*)alloc((size_t)BATCH * SEQ * NH * 2);
    bf16* a_bf    = (bf16*)alloc((size_t)BATCH * SEQ * DMODEL * 2);
    bf16* wt_qkv  = (bf16*)alloc((size_t)QKVN * DMODEL * 2);
    bf16* wt_out  = (bf16*)alloc((size_t)NH * DMODEL * 2);
    bf16* wt_pos  = (bf16*)alloc((size_t)NH * FREQS * 2);

    const float qkv_scale = (float)pow(3.0 * DMODEL * HSIZE * HEADS, -0.25);
    const float emb_scale = 0.0625f;   // 256^-0.5
    const float out_scale = 0.03125f;  // (1024*1024)^-0.25

    // 1. merged prep (cast + sins + 3 transposes)
    prep_kernel<<<10496, 256, 0, stream>>>(
        inp, qkv_w, out_kernel, positional, a_bf, wt_qkv, wt_out, wt_pos, sins_bf);

    // 2. merged QKV projection + emb GEMM
    mfma_gemm<1><<<dim3(32, 32), 256, 0, stream>>>(
        a_bf, wt_qkv, DMODEL, qkv_scale, q_bias, nullptr, qbuf, kbuf, vtbuf,
        sins_bf, wt_pos, embT, emb_scale);

    // 3. flash attention -> bf16 o
    attn_kernel<<<dim3(32, 16), 256, 0, stream>>>(
        qbuf, kbuf, vtbuf, embT, obuf);

    // 4. output projection (fp32 out)
    mfma_gemm<0><<<dim3(8, 32), 256, 0, stream>>>(
        obuf, wt_out, DMODEL, out_scale, out_bias, (float*)d_out,
        nullptr, nullptr, nullptr, nullptr, nullptr, nullptr, 0.0f);
}